// Round 1
// baseline (2903.402 us; speedup 1.0000x reference)
//
#include <hip/hip_runtime.h>
#include <math.h>

#define N_IMG  512
#define N_Z    8
#define N_VIEW 360
#define N_DET  512
#define N_S    512

// One block per (z, view); one thread per detector.
// blockIdx.x = z * N_VIEW + view  (consecutive blocks share the same slice -> L2 reuse)
__global__ __launch_bounds__(512) void proj_kernel(const float* __restrict__ vol,
                                                   float* __restrict__ out) {
    const int blk  = blockIdx.x;
    const int z    = blk / N_VIEW;
    const int view = blk - z * N_VIEW;
    const int det  = threadIdx.x;

    // theta = view * f32(pi/360), matching jnp.arange(f32) * (np.pi/N_VIEW)
    const float theta = (float)view * 0.008726646f; // f32 rounding of pi/360
    float si, c;
    sincosf(theta, &si, &c);

    const float half = (float)(N_IMG - 1) * 0.5f;   // 255.5
    const float t    = (float)det - (float)(N_DET - 1) * 0.5f;
    // ix(s) = c*s + bx ; iy(s) = si*s + by
    const float bx = half - si * t;
    const float by = half + c  * t;
    const float s0 = -(float)(N_S - 1) * 0.5f;      // -255.5

    // Clip s-range where the sample can touch the image:
    // need ix in (-1, 512) AND iy in (-1, 512). Conservative margins; samples
    // outside the true support contribute exactly 0 via mask weights anyway.
    float lo = -1e30f, hi = 1e30f;
    {
        // axis x: dir=c, offset=bx
        if (fabsf(c) > 1e-7f) {
            float sA = (-1.0f - bx) / c;
            float sB = (512.0f - bx) / c;
            lo = fmaxf(lo, fminf(sA, sB));
            hi = fminf(hi, fmaxf(sA, sB));
        } else if (bx <= -1.0f || bx >= 512.0f) {
            lo = 1e30f; hi = -1e30f;
        }
        // axis y: dir=si, offset=by
        if (fabsf(si) > 1e-7f) {
            float sA = (-1.0f - by) / si;
            float sB = (512.0f - by) / si;
            lo = fmaxf(lo, fminf(sA, sB));
            hi = fminf(hi, fmaxf(sA, sB));
        } else if (by <= -1.0f || by >= 512.0f) {
            lo = 1e30f; hi = -1e30f;
        }
    }
    int klo = 0, khi = -1;
    if (hi >= lo) {
        klo = max(0, (int)floorf(lo - s0) - 1);
        khi = min(N_S - 1, (int)ceilf(hi - s0) + 1);
    }

    const float* __restrict__ img = vol + (size_t)z * (N_IMG * N_IMG);

    float acc = 0.0f;
    for (int k = klo; k <= khi; ++k) {
        const float sk = s0 + (float)k;            // exact (x.5 values)
        const float px = fmaf(c,  sk, bx);         // ix coordinate (col)
        const float py = fmaf(si, sk, by);         // iy coordinate (row)
        const float fx = floorf(px);
        const float fy = floorf(py);
        const float wx = px - fx;
        const float wy = py - fy;
        const int ix = (int)fx;
        const int iy = (int)fy;

        // clamped addresses (always in-bounds, uniform control flow)
        const int ix0 = min(max(ix,     0), N_IMG - 1);
        const int ix1 = min(max(ix + 1, 0), N_IMG - 1);
        const int iy0 = min(max(iy,     0), N_IMG - 1);
        const int iy1 = min(max(iy + 1, 0), N_IMG - 1);

        const bool x0v = (unsigned)(ix)     < (unsigned)N_IMG;
        const bool x1v = (unsigned)(ix + 1) < (unsigned)N_IMG;
        const bool y0v = (unsigned)(iy)     < (unsigned)N_IMG;
        const bool y1v = (unsigned)(iy + 1) < (unsigned)N_IMG;

        const float* __restrict__ r0 = img + iy0 * N_IMG;
        const float* __restrict__ r1 = img + iy1 * N_IMG;
        const float a00 = r0[ix0];
        const float a01 = r0[ix1];
        const float a10 = r1[ix0];
        const float a11 = r1[ix1];

        const float wx0 = 1.0f - wx;
        const float wy0 = 1.0f - wy;
        const float w00 = (x0v && y0v) ? wy0 * wx0 : 0.0f;
        const float w01 = (x1v && y0v) ? wy0 * wx  : 0.0f;
        const float w10 = (x0v && y1v) ? wy  * wx0 : 0.0f;
        const float w11 = (x1v && y1v) ? wy  * wx  : 0.0f;

        acc = fmaf(a00, w00, acc);
        acc = fmaf(a01, w01, acc);
        acc = fmaf(a10, w10, acc);
        acc = fmaf(a11, w11, acc);
    }

    // DS = 1.0 ; out shape (Z, 1, V, D)
    out[((size_t)z * N_VIEW + view) * N_DET + det] = acc;
}

extern "C" void kernel_launch(void* const* d_in, const int* in_sizes, int n_in,
                              void* d_out, int out_size, void* d_ws, size_t ws_size,
                              hipStream_t stream) {
    const float* vol = (const float*)d_in[0];
    float* out = (float*)d_out;
    (void)in_sizes; (void)n_in; (void)out_size; (void)d_ws; (void)ws_size;
    proj_kernel<<<dim3(N_Z * N_VIEW), dim3(512), 0, stream>>>(vol, out);
}

// Round 4
// 2202.742 us; speedup vs baseline: 1.3181x; 1.3181x over previous
//
#include <hip/hip_runtime.h>
#include <math.h>

#define N_IMG  512
#define N_Z    8
#define N_VIEW 360
#define N_DET  512
#define N_S    512
#define SLICE  (N_IMG * N_IMG)

// volT[z][x][y] = vol[z][y][x]
__global__ __launch_bounds__(256) void transpose_kernel(const float* __restrict__ in,
                                                        float* __restrict__ out) {
    __shared__ float tile[32][33];
    const int nbx = N_IMG / 32;                 // 16
    const int bx = blockIdx.x % nbx;
    const int by = (blockIdx.x / nbx) % nbx;
    const int z  = blockIdx.x / (nbx * nbx);
    const float* __restrict__ src = in  + (size_t)z * SLICE;
    float* __restrict__ dst       = out + (size_t)z * SLICE;
    const int lx = threadIdx.x & 31;
    const int ly = threadIdx.x >> 5;            // 0..7
    #pragma unroll
    for (int i = 0; i < 32; i += 8)
        tile[ly + i][lx] = src[(by * 32 + ly + i) * N_IMG + bx * 32 + lx];
    __syncthreads();
    #pragma unroll
    for (int i = 0; i < 32; i += 8)
        dst[(bx * 32 + ly + i) * N_IMG + by * 32 + lx] = tile[lx][ly + i];
}

// Block = (view, det-group of 128). 512 threads = 8 waves.
// Wave lane = tl*4 + kp : 16 detectors x 4 s-phases  (shrinks per-load row span).
// Inner loop: compute coords/weights once, apply to all 8 z-slices (32 loads).
__global__ __launch_bounds__(512) void proj_kernel(const float* __restrict__ vol,
                                                   const float* __restrict__ volT,
                                                   float* __restrict__ out,
                                                   int useT) {
    const int blk  = blockIdx.x;
    const int view = blk >> 2;
    const int dg   = blk & 3;
    const int tid  = threadIdx.x;
    const int lane = tid & 63;
    const int wv   = tid >> 6;                  // 0..7
    const int kp   = lane & 3;                  // s-phase
    const int tl   = lane >> 2;                 // 0..15
    const int det  = dg * 128 + wv * 16 + tl;

    const float theta = (float)view * (float)(M_PI / 360.0);
    float si, c;
    sincosf(theta, &si, &c);

    const float half = 255.5f;
    const float t    = (float)det - 255.5f;
    const float s0   = -255.5f;

    // Layout choice: make the per-detector (lane) step along the fast axis big.
    // L0 (row-major vol):  u=x: au=c,  du=-si ; v=y: av=si, dv=c
    // L1 (transposed):     u=y: au=si, du=c  ; v=x: av=c,  dv=-si
    const int   L1sel = useT && (fabsf(c) > fabsf(si));
    const float au = L1sel ? si  : c;
    const float du = L1sel ? c   : -si;
    const float av = L1sel ? c   : si;
    const float dv = L1sel ? -si : c;
    const float* __restrict__ base = L1sel ? volT : vol;

    const float bu = fmaf(du, t, half);
    const float bv = fmaf(dv, t, half);

    // Clip s to where any tap can be nonzero: u in [-1,512], v in [-1,512].
    float lo = -1e30f, hi = 1e30f;
    {
        if (fabsf(au) > 1e-7f) {
            float sA = (-1.0f - bu) / au;
            float sB = (512.0f - bu) / au;
            lo = fmaxf(lo, fminf(sA, sB));
            hi = fminf(hi, fmaxf(sA, sB));
        } else if (bu <= -1.0f || bu >= 512.0f) { lo = 1e30f; hi = -1e30f; }
        if (fabsf(av) > 1e-7f) {
            float sA = (-1.0f - bv) / av;
            float sB = (512.0f - bv) / av;
            lo = fmaxf(lo, fminf(sA, sB));
            hi = fminf(hi, fmaxf(sA, sB));
        } else if (bv <= -1.0f || bv >= 512.0f) { lo = 1e30f; hi = -1e30f; }
    }
    int klo = 0, khi = -1;
    if (hi >= lo) {
        klo = max(0, (int)floorf(lo - s0) - 1);
        khi = min(N_S - 1, (int)ceilf(hi - s0) + 1);
    }
    const int kstart = (klo & ~3) + kp;

    float acc[N_Z];
    #pragma unroll
    for (int z = 0; z < N_Z; z++) acc[z] = 0.0f;

    for (int k = kstart; k <= khi; k += 4) {
        const float sk = s0 + (float)k;
        const float u  = fmaf(au, sk, bu);
        const float v  = fmaf(av, sk, bv);
        const float fu = floorf(u);
        const float fv = floorf(v);
        const float wu = u - fu;
        const float wv_ = v - fv;
        const int iu = (int)fu;
        const int iv = (int)fv;

        const int iu0 = min(max(iu,     0), N_IMG - 1);
        const int iu1 = min(max(iu + 1, 0), N_IMG - 1);
        const int iv0 = min(max(iv,     0), N_IMG - 1);
        const int iv1 = min(max(iv + 1, 0), N_IMG - 1);

        const bool u0v = (unsigned)(iu)     < (unsigned)N_IMG;
        const bool u1v = (unsigned)(iu + 1) < (unsigned)N_IMG;
        const bool v0v = (unsigned)(iv)     < (unsigned)N_IMG;
        const bool v1v = (unsigned)(iv + 1) < (unsigned)N_IMG;

        const float wu0 = 1.0f - wu;
        const float wv0 = 1.0f - wv_;
        const float w00 = (v0v && u0v) ? wv0 * wu0 : 0.0f;
        const float w01 = (v0v && u1v) ? wv0 * wu  : 0.0f;
        const float w10 = (v1v && u0v) ? wv_ * wu0 : 0.0f;
        const float w11 = (v1v && u1v) ? wv_ * wu  : 0.0f;

        const int o00 = iv0 * N_IMG + iu0;
        const int o01 = iv0 * N_IMG + iu1;
        const int o10 = iv1 * N_IMG + iu0;
        const int o11 = iv1 * N_IMG + iu1;

        #pragma unroll
        for (int z = 0; z < N_Z; z++) {
            const float* __restrict__ b = base + (size_t)z * SLICE;
            acc[z] = fmaf(b[o00], w00, acc[z]);
            acc[z] = fmaf(b[o01], w01, acc[z]);
            acc[z] = fmaf(b[o10], w10, acc[z]);
            acc[z] = fmaf(b[o11], w11, acc[z]);
        }
    }

    // Sum the 4 s-phases (lanes tl*4 .. tl*4+3).
    #pragma unroll
    for (int z = 0; z < N_Z; z++) {
        acc[z] += __shfl_xor(acc[z], 1);
        acc[z] += __shfl_xor(acc[z], 2);
    }
    // Each of the 4 phase-lanes writes 2 z's. out shape (Z,1,V,D).
    #pragma unroll
    for (int j = 0; j < 2; j++) {
        const int z = kp * 2 + j;
        out[((size_t)(z * N_VIEW + view)) * N_DET + det] = acc[z];
    }
}

extern "C" void kernel_launch(void* const* d_in, const int* in_sizes, int n_in,
                              void* d_out, int out_size, void* d_ws, size_t ws_size,
                              hipStream_t stream) {
    const float* vol = (const float*)d_in[0];
    float* out = (float*)d_out;
    (void)in_sizes; (void)n_in; (void)out_size;

    const size_t tneed = (size_t)N_Z * SLICE * sizeof(float);   // 8 MB
    if (ws_size >= tneed) {
        float* volT = (float*)d_ws;
        transpose_kernel<<<dim3((N_IMG/32)*(N_IMG/32)*N_Z), dim3(256), 0, stream>>>(vol, volT);
        proj_kernel<<<dim3(N_VIEW * 4), dim3(512), 0, stream>>>(vol, volT, out, 1);
    } else {
        proj_kernel<<<dim3(N_VIEW * 4), dim3(512), 0, stream>>>(vol, vol, out, 0);
    }
}

// Round 5
// 1614.928 us; speedup vs baseline: 1.7979x; 1.3640x over previous
//
#include <hip/hip_runtime.h>
#include <math.h>

#define N_IMG  512
#define N_Z    8
#define N_VIEW 360
#define N_DET  512
#define N_S    512
#define SLICE  (N_IMG * N_IMG)

#define DG     64          // detectors per block
#define SC     32          // s-samples per chunk
#define NCHUNK (N_S / SC)  // 16
#define ROWS_MAX 76        // window rows bound (proven <= 74)
#define STRIDE   81        // odd stride -> rows spread across banks

// Block = (view, det-group of 64). 256 threads = 4 waves.
// Lane = 16 dets x 4 s-phases. Per s-chunk: stage the rotated-rect bounding
// window into LDS (zero-filled outside image -> cval=0 automatic), cache each
// sample's (offset, wu, wv) in regs, then loop z=0..7 restaging the window and
// gathering from LDS. Global traffic is coalesced rows; gathers hit LDS.
__global__ __launch_bounds__(256) void proj_kernel(const float* __restrict__ vol,
                                                   float* __restrict__ out) {
    __shared__ float sm[ROWS_MAX * STRIDE];

    const int bid  = blockIdx.x;
    const int view = bid >> 3;
    const int dg   = bid & 7;
    const int tid  = threadIdx.x;
    const int lane = tid & 63;
    const int wvid = tid >> 6;                 // wave 0..3
    const int kp   = lane & 3;                 // s-phase
    const int tl   = lane >> 2;                // 0..15
    const int det  = dg * DG + wvid * 16 + tl;

    const float theta = (float)view * (float)(M_PI / 360.0);
    float si, c;
    sincosf(theta, &si, &c);

    const float t  = (float)det - 255.5f;
    const float bu = fmaf(-si, t, 255.5f);     // u = c*s + bu  (image col)
    const float bv = fmaf( c,  t, 255.5f);     // v = si*s + bv (image row)

    // Conservative ray clip: k-range where any tap can be nonzero.
    float lo = -1e30f, hi = 1e30f;
    {
        if (fabsf(c) > 1e-7f) {
            float a = (-1.0f - bu) / c;
            float b = (512.0f - bu) / c;
            lo = fmaxf(lo, fminf(a, b));
            hi = fminf(hi, fmaxf(a, b));
        } else if (bu <= -1.0f || bu >= 512.0f) { lo = 1e30f; hi = -1e30f; }
        if (fabsf(si) > 1e-7f) {
            float a = (-1.0f - bv) / si;
            float b = (512.0f - bv) / si;
            lo = fmaxf(lo, fminf(a, b));
            hi = fminf(hi, fmaxf(a, b));
        } else if (bv <= -1.0f || bv >= 512.0f) { lo = 1e30f; hi = -1e30f; }
    }
    int klo = 0, khi = -1;
    if (hi >= lo) {
        klo = max(0, (int)floorf(lo + 255.5f) - 1);
        khi = min(N_S - 1, (int)ceilf(hi + 255.5f) + 1);
    }

    const float tA = (float)(dg * DG) - 255.5f;   // block det-range corners
    const float tB = tA + (float)(DG - 1);

    float acc[N_Z];
    #pragma unroll
    for (int z = 0; z < N_Z; z++) acc[z] = 0.0f;

    for (int ck = 0; ck < NCHUNK; ++ck) {
        const int kbase = ck * SC;
        const float sA = -255.5f + (float)kbase;
        const float sB = sA + (float)(SC - 1);

        // Window corners (block-uniform).
        const float buA = fmaf(-si, tA, 255.5f), buB = fmaf(-si, tB, 255.5f);
        const float bvA = fmaf( c,  tA, 255.5f), bvB = fmaf( c,  tB, 255.5f);
        const float u00 = fmaf(c, sA, buA), u01 = fmaf(c, sB, buA);
        const float u10 = fmaf(c, sA, buB), u11 = fmaf(c, sB, buB);
        const float v00 = fmaf(si, sA, bvA), v01 = fmaf(si, sB, bvA);
        const float v10 = fmaf(si, sA, bvB), v11 = fmaf(si, sB, bvB);
        const float umin = fminf(fminf(u00, u01), fminf(u10, u11));
        const float umax = fmaxf(fmaxf(u00, u01), fmaxf(u10, u11));
        const float vmin = fminf(fminf(v00, v01), fminf(v10, v11));
        const float vmax = fmaxf(fmaxf(v00, v01), fmaxf(v10, v11));

        const int u0c = (int)floorf(umin) - 1;
        const int v0c = (int)floorf(vmin) - 1;
        int WU = (int)floorf(umax) - u0c + 2;      // cols needed (<= 74)
        int WV = (int)floorf(vmax) - v0c + 2;      // rows needed (<= 74)
        WU = min(WU, STRIDE - 1);                  // safety (never binds)
        WV = min(WV, ROWS_MAX);

        // Window entirely off-image -> zero contribution for everyone.
        if (u0c >= N_IMG || v0c >= N_IMG || u0c + WU <= 0 || v0c + WV <= 0)
            continue;

        const bool active = (klo <= kbase + SC - 1) && (khi >= kbase);

        int   offs[8];
        float wus[8], wvs[8];
        if (active) {
            #pragma unroll
            for (int j = 0; j < 8; j++) {
                const int k = kbase + j * 4 + kp;
                const float s = -255.5f + (float)k;
                const float u = fmaf(c,  s, bu);
                const float v = fmaf(si, s, bv);
                const float fu = floorf(u);
                const float fv = floorf(v);
                wus[j] = u - fu;
                wvs[j] = v - fv;
                offs[j] = ((int)fv - v0c) * STRIDE + ((int)fu - u0c);
            }
        }

        const int cnt = __syncthreads_count(active ? 1 : 0);
        if (cnt == 0) continue;

        #pragma unroll
        for (int z = 0; z < N_Z; ++z) {
            const float* __restrict__ img = vol + (size_t)z * SLICE;
            // Stage window rows (zero-filled outside the image).
            for (int j = wvid; j < WV; j += 4) {
                const int r = v0c + j;
                const bool rok = (unsigned)r < (unsigned)N_IMG;
                float* dstrow = &sm[j * STRIDE];
                if (lane < WU) {
                    const int cc = u0c + lane;
                    float vl = 0.0f;
                    if (rok && (unsigned)cc < (unsigned)N_IMG) vl = img[r * N_IMG + cc];
                    dstrow[lane] = vl;
                }
                if (lane < WU - 64) {
                    const int cc = u0c + 64 + lane;
                    float vl = 0.0f;
                    if (rok && (unsigned)cc < (unsigned)N_IMG) vl = img[r * N_IMG + cc];
                    dstrow[64 + lane] = vl;
                }
            }
            __syncthreads();
            if (active) {
                #pragma unroll
                for (int j = 0; j < 8; j++) {
                    const int o = offs[j];
                    const float a00 = sm[o],          a01 = sm[o + 1];
                    const float a10 = sm[o + STRIDE], a11 = sm[o + STRIDE + 1];
                    const float wu = wus[j], wv2 = wvs[j];
                    const float top = fmaf(wu, a01 - a00, a00);
                    const float bot = fmaf(wu, a11 - a10, a10);
                    acc[z] = fmaf(wv2, bot - top, acc[z] + top);
                }
            }
            __syncthreads();
        }
    }

    // Combine the 4 s-phases (lanes tl*4 .. tl*4+3).
    #pragma unroll
    for (int z = 0; z < N_Z; z++) {
        acc[z] += __shfl_xor(acc[z], 1);
        acc[z] += __shfl_xor(acc[z], 2);
    }
    // Lane phase kp writes z = 2*kp and 2*kp+1 (static-index select, no scratch).
    #pragma unroll
    for (int j = 0; j < 2; j++) {
        const int zt = kp * 2 + j;
        float val = 0.0f;
        #pragma unroll
        for (int zz = 0; zz < N_Z; zz++)
            if (zz == zt) val = acc[zz];
        out[((size_t)(zt * N_VIEW + view)) * N_DET + det] = val;
    }
}

extern "C" void kernel_launch(void* const* d_in, const int* in_sizes, int n_in,
                              void* d_out, int out_size, void* d_ws, size_t ws_size,
                              hipStream_t stream) {
    const float* vol = (const float*)d_in[0];
    float* out = (float*)d_out;
    (void)in_sizes; (void)n_in; (void)out_size; (void)d_ws; (void)ws_size;
    proj_kernel<<<dim3(N_VIEW * 8), dim3(256), 0, stream>>>(vol, out);
}

// Round 6
// 962.930 us; speedup vs baseline: 3.0152x; 1.6771x over previous
//
#include <hip/hip_runtime.h>
#include <hip/hip_fp16.h>
#include <math.h>

#define N_IMG  512
#define N_Z    8
#define N_VIEW 360
#define N_DET  512
#define N_S    512
#define SLICE  (N_IMG * N_IMG)

// ---- fast path config ----
// Padded fp16 vertical-pair volume in ws:
//   PV[zz][r][c] = half2( P(r-2, c-2), P(r-1, c-2) ),  P = vol zero-padded.
// r in [0,514] covers pair-row civ in [-2,512]; c in [0,515] covers col in [-2,513].
#define PV_ROWS    515
#define PV_PITCH   516
#define PV_ZSTRIDE (PV_ROWS * PV_PITCH)   // u32 units
#define ZB 4          // z slices per pass (2 passes)
#define NV 4          // views per block (one per wave)
#define DG 32         // detectors per block
#define SC 32         // s samples per chunk
#define NCHUNK (N_S / SC)
#define ST 68         // LDS row stride in u32 (68 mod 32 == 4 -> conflict-free map)
#define ROWS_MAX 60   // window rows bound (proven <= 57)

__global__ __launch_bounds__(256) void pad_kernel(const float* __restrict__ vol,
                                                  unsigned* __restrict__ pv, int zbase) {
    const int zr = blockIdx.x;                  // 0 .. ZB*PV_ROWS-1
    const int zz = zr / PV_ROWS;
    const int r  = zr - zz * PV_ROWS;
    const float* __restrict__ img = vol + (size_t)(zbase + zz) * SLICE;
    unsigned* __restrict__ dst = pv + (size_t)zz * PV_ZSTRIDE + (size_t)r * PV_PITCH;
    const int y0 = r - 2, y1 = r - 1;
    const bool y0ok = (unsigned)y0 < (unsigned)N_IMG;
    const bool y1ok = (unsigned)y1 < (unsigned)N_IMG;
    for (int c = threadIdx.x; c < PV_PITCH; c += 256) {
        const int x = c - 2;
        const bool xok = (unsigned)x < (unsigned)N_IMG;
        const float v0 = (y0ok && xok) ? img[y0 * N_IMG + x] : 0.0f;
        const float v1 = (y1ok && xok) ? img[y1 * N_IMG + x] : 0.0f;
        __half2 h;
        h.x = __float2half(v0);
        h.y = __float2half(v1);
        dst[c] = *reinterpret_cast<unsigned*>(&h);
    }
}

// Block: 4 views (one per wave) x 32 dets x full s. Lane = 8 dets x 8 s-phases.
// Per chunk: union window over the 4 views staged once per z (fp16 vpairs);
// gather = ONE ds_read2_b32 per bilinear sample. Clamp+pad => cval=0 exact.
__global__ __launch_bounds__(256, 4) void proj_kernel(const unsigned* __restrict__ pv,
                                                      float* __restrict__ out, int zbase) {
    __shared__ unsigned sm[ROWS_MAX * ST];

    const int g    = blockIdx.x >> 4;          // view group 0..89
    const int dg   = blockIdx.x & 15;          // det group 0..15
    const int tid  = threadIdx.x;
    const int wvid = tid >> 6;                 // wave -> view
    const int lane = tid & 63;
    const int kp   = lane & 7;                 // s-phase
    const int tl   = lane >> 3;                // det-lane 0..7
    const int view = g * NV + wvid;

    const float KTH = (float)(M_PI / 360.0);
    float c0, s0, c1, s1, c2, s2, c3, s3;
    sincosf((float)(g * 4 + 0) * KTH, &s0, &c0);
    sincosf((float)(g * 4 + 1) * KTH, &s1, &c1);
    sincosf((float)(g * 4 + 2) * KTH, &s2, &c2);
    sincosf((float)(g * 4 + 3) * KTH, &s3, &c3);
    const float c_my = (wvid == 0) ? c0 : (wvid == 1) ? c1 : (wvid == 2) ? c2 : c3;
    const float s_my = (wvid == 0) ? s0 : (wvid == 1) ? s1 : (wvid == 2) ? s2 : s3;

    const float t_base = (float)(dg * DG) - 255.5f;
    float buv[4], bvv[4];
    #pragma unroll
    for (int dd = 0; dd < 4; dd++) {
        const float tt = t_base + (float)(dd * 8 + tl);
        buv[dd] = fmaf(-s_my, tt, 255.5f);     // u = c*s + buv
        bvv[dd] = fmaf( c_my, tt, 255.5f);     // v = si*s + bvv
    }

    float acc[4][ZB];
    #pragma unroll
    for (int dd = 0; dd < 4; dd++)
        #pragma unroll
        for (int zz = 0; zz < ZB; zz++) acc[dd][zz] = 0.0f;

    for (int ck = 0; ck < NCHUNK; ++ck) {
        const float sA = (float)(ck * SC) - 255.5f;
        const float sB = sA + (float)(SC - 1);
        const float tA = t_base, tB = t_base + (float)(DG - 1);

        // Union bbox over the 4 views (separable corner min/max).
        float umin = 1e30f, umax = -1e30f, vmin = 1e30f, vmax = -1e30f;
        #pragma unroll
        for (int i = 0; i < 4; i++) {
            const float ci = (i == 0) ? c0 : (i == 1) ? c1 : (i == 2) ? c2 : c3;
            const float si = (i == 0) ? s0 : (i == 1) ? s1 : (i == 2) ? s2 : s3;
            const float ua = ci * sA, ub = ci * sB;
            const float uc = -si * tA, ud = -si * tB;
            umin = fminf(umin, fminf(ua, ub) + fminf(uc, ud));
            umax = fmaxf(umax, fmaxf(ua, ub) + fmaxf(uc, ud));
            const float va = si * sA, vb = si * sB;
            const float vc = ci * tA, vd = ci * tB;
            vmin = fminf(vmin, fminf(va, vb) + fminf(vc, vd));
            vmax = fmaxf(vmax, fmaxf(va, vb) + fmaxf(vc, vd));
        }
        umin += 255.5f; umax += 255.5f; vmin += 255.5f; vmax += 255.5f;

        const int u0   = max((int)floorf(umin) - 1, -2);
        const int uend = min((int)floorf(umax) + 2, 513);
        const int v0   = max((int)floorf(vmin) - 1, -2);
        const int vend = min((int)floorf(vmax) + 1, 512);
        if (uend < u0 || vend < v0) continue;          // block-uniform
        const int WU = min(uend - u0 + 1, ST);
        const int WV = min(vend - v0 + 1, ROWS_MAX);

        // Per-thread sample offsets/weights (shared across z).
        int   offs[4][4];
        float wua[4][4], wva[4][4];
        bool  act[4];
        #pragma unroll
        for (int dd = 0; dd < 4; dd++) {
            const float uA = fmaf(c_my, sA, buv[dd]), uB = fmaf(c_my, sB, buv[dd]);
            const float vA = fmaf(s_my, sA, bvv[dd]), vB = fmaf(s_my, sB, bvv[dd]);
            const float ulo = fminf(uA, uB), uhi = fmaxf(uA, uB);
            const float vlo = fminf(vA, vB), vhi = fmaxf(vA, vB);
            act[dd] = (uhi > -1.0f) && (ulo < 512.0f) && (vhi > -1.0f) && (vlo < 512.0f);
            if (act[dd]) {
                #pragma unroll
                for (int ks = 0; ks < 4; ks++) {
                    const float s = sA + (float)(ks * 8 + kp);
                    const float u = fmaf(c_my, s, buv[dd]);
                    const float v = fmaf(s_my, s, bvv[dd]);
                    const float fu = floorf(u), fv = floorf(v);
                    wua[dd][ks] = u - fu;
                    wva[dd][ks] = v - fv;
                    const int ciu = min(max((int)fu, -2), 512);
                    const int civ = min(max((int)fv, -2), 512);
                    offs[dd][ks] = (civ - v0) * ST + (ciu - u0);
                }
            }
        }

        #pragma unroll
        for (int zz = 0; zz < ZB; zz++) {
            __syncthreads();    // previous gather done before overwrite
            const unsigned* __restrict__ src = pv + (size_t)zz * PV_ZSTRIDE
                                             + (size_t)(v0 + 2) * PV_PITCH + (u0 + 2);
            if (lane < WU)
                for (int r = wvid; r < WV; r += 4)
                    sm[r * ST + lane] = src[r * PV_PITCH + lane];
            __syncthreads();
            #pragma unroll
            for (int dd = 0; dd < 4; dd++) {
                if (act[dd]) {
                    #pragma unroll
                    for (int ks = 0; ks < 4; ks++) {
                        const int o = offs[dd][ks];
                        const unsigned p0 = sm[o], p1 = sm[o + 1];
                        const __half2 h0 = *reinterpret_cast<const __half2*>(&p0);
                        const __half2 h1 = *reinterpret_cast<const __half2*>(&p1);
                        const float2 f0 = __half22float2(h0);  // x: row civ, y: row civ+1
                        const float2 f1 = __half22float2(h1);
                        const float wu = wua[dd][ks], wv = wva[dd][ks];
                        const float top = fmaf(wu, f1.x - f0.x, f0.x);
                        const float bot = fmaf(wu, f1.y - f0.y, f0.y);
                        acc[dd][zz] = fmaf(wv, bot - top, acc[dd][zz] + top);
                    }
                }
            }
        }
    }

    // Reduce the 8 s-phases; lanes kp<ZB write z = zbase+kp.
    #pragma unroll
    for (int dd = 0; dd < 4; dd++) {
        #pragma unroll
        for (int zz = 0; zz < ZB; zz++) {
            float a = acc[dd][zz];
            a += __shfl_xor(a, 1);
            a += __shfl_xor(a, 2);
            a += __shfl_xor(a, 4);
            acc[dd][zz] = a;
        }
        if (kp < ZB) {
            float val = acc[dd][0];
            if (kp == 1) val = acc[dd][1];
            else if (kp == 2) val = acc[dd][2];
            else if (kp == 3) val = acc[dd][3];
            const int det = dg * DG + dd * 8 + tl;
            out[((size_t)((zbase + kp) * N_VIEW + view)) * N_DET + det] = val;
        }
    }
}

// ---------------- fallback (Round-5 kernel, no ws needed) ----------------
#define FDG 64
#define FSC 32
#define FNC (N_S / FSC)
#define FROWS 76
#define FSTR  81

__global__ __launch_bounds__(256) void proj_fallback(const float* __restrict__ vol,
                                                     float* __restrict__ out) {
    __shared__ float sm[FROWS * FSTR];
    const int bid  = blockIdx.x;
    const int view = bid >> 3;
    const int dg   = bid & 7;
    const int tid  = threadIdx.x;
    const int lane = tid & 63;
    const int wvid = tid >> 6;
    const int kp   = lane & 3;
    const int tl   = lane >> 2;
    const int det  = dg * FDG + wvid * 16 + tl;

    const float theta = (float)view * (float)(M_PI / 360.0);
    float si, c;
    sincosf(theta, &si, &c);
    const float t  = (float)det - 255.5f;
    const float bu = fmaf(-si, t, 255.5f);
    const float bv = fmaf( c,  t, 255.5f);

    float lo = -1e30f, hi = 1e30f;
    if (fabsf(c) > 1e-7f) {
        float a = (-1.0f - bu) / c, b = (512.0f - bu) / c;
        lo = fmaxf(lo, fminf(a, b)); hi = fminf(hi, fmaxf(a, b));
    } else if (bu <= -1.0f || bu >= 512.0f) { lo = 1e30f; hi = -1e30f; }
    if (fabsf(si) > 1e-7f) {
        float a = (-1.0f - bv) / si, b = (512.0f - bv) / si;
        lo = fmaxf(lo, fminf(a, b)); hi = fminf(hi, fmaxf(a, b));
    } else if (bv <= -1.0f || bv >= 512.0f) { lo = 1e30f; hi = -1e30f; }
    int klo = 0, khi = -1;
    if (hi >= lo) {
        klo = max(0, (int)floorf(lo + 255.5f) - 1);
        khi = min(N_S - 1, (int)ceilf(hi + 255.5f) + 1);
    }
    const float tA = (float)(dg * FDG) - 255.5f;
    const float tB = tA + (float)(FDG - 1);

    float acc[N_Z];
    #pragma unroll
    for (int z = 0; z < N_Z; z++) acc[z] = 0.0f;

    for (int ck = 0; ck < FNC; ++ck) {
        const int kbase = ck * FSC;
        const float sA = -255.5f + (float)kbase;
        const float sB = sA + (float)(FSC - 1);
        const float buA = fmaf(-si, tA, 255.5f), buB = fmaf(-si, tB, 255.5f);
        const float bvA = fmaf( c,  tA, 255.5f), bvB = fmaf( c,  tB, 255.5f);
        const float u00 = fmaf(c, sA, buA), u01 = fmaf(c, sB, buA);
        const float u10 = fmaf(c, sA, buB), u11 = fmaf(c, sB, buB);
        const float v00 = fmaf(si, sA, bvA), v01 = fmaf(si, sB, bvA);
        const float v10 = fmaf(si, sA, bvB), v11 = fmaf(si, sB, bvB);
        const float umin = fminf(fminf(u00, u01), fminf(u10, u11));
        const float umax = fmaxf(fmaxf(u00, u01), fmaxf(u10, u11));
        const float vmin = fminf(fminf(v00, v01), fminf(v10, v11));
        const float vmax = fmaxf(fmaxf(v00, v01), fmaxf(v10, v11));
        const int u0c = (int)floorf(umin) - 1;
        const int v0c = (int)floorf(vmin) - 1;
        int WU = (int)floorf(umax) - u0c + 2;
        int WV = (int)floorf(vmax) - v0c + 2;
        WU = min(WU, FSTR - 1); WV = min(WV, FROWS);
        if (u0c >= N_IMG || v0c >= N_IMG || u0c + WU <= 0 || v0c + WV <= 0) continue;
        const bool active = (klo <= kbase + FSC - 1) && (khi >= kbase);
        int offs[8]; float wus[8], wvs[8];
        if (active) {
            #pragma unroll
            for (int j = 0; j < 8; j++) {
                const int k = kbase + j * 4 + kp;
                const float s = -255.5f + (float)k;
                const float u = fmaf(c, s, bu), v = fmaf(si, s, bv);
                const float fu = floorf(u), fv = floorf(v);
                wus[j] = u - fu; wvs[j] = v - fv;
                offs[j] = ((int)fv - v0c) * FSTR + ((int)fu - u0c);
            }
        }
        const int cnt = __syncthreads_count(active ? 1 : 0);
        if (cnt == 0) continue;
        #pragma unroll
        for (int z = 0; z < N_Z; ++z) {
            const float* __restrict__ img = vol + (size_t)z * SLICE;
            for (int j = wvid; j < WV; j += 4) {
                const int r = v0c + j;
                const bool rok = (unsigned)r < (unsigned)N_IMG;
                float* dstrow = &sm[j * FSTR];
                if (lane < WU) {
                    const int cc = u0c + lane;
                    float vl = 0.0f;
                    if (rok && (unsigned)cc < (unsigned)N_IMG) vl = img[r * N_IMG + cc];
                    dstrow[lane] = vl;
                }
                if (lane < WU - 64) {
                    const int cc = u0c + 64 + lane;
                    float vl = 0.0f;
                    if (rok && (unsigned)cc < (unsigned)N_IMG) vl = img[r * N_IMG + cc];
                    dstrow[64 + lane] = vl;
                }
            }
            __syncthreads();
            if (active) {
                #pragma unroll
                for (int j = 0; j < 8; j++) {
                    const int o = offs[j];
                    const float a00 = sm[o], a01 = sm[o + 1];
                    const float a10 = sm[o + FSTR], a11 = sm[o + FSTR + 1];
                    const float wu = wus[j], wv2 = wvs[j];
                    const float top = fmaf(wu, a01 - a00, a00);
                    const float bot = fmaf(wu, a11 - a10, a10);
                    acc[z] = fmaf(wv2, bot - top, acc[z] + top);
                }
            }
            __syncthreads();
        }
    }
    #pragma unroll
    for (int z = 0; z < N_Z; z++) {
        acc[z] += __shfl_xor(acc[z], 1);
        acc[z] += __shfl_xor(acc[z], 2);
    }
    #pragma unroll
    for (int j = 0; j < 2; j++) {
        const int zt = kp * 2 + j;
        float val = 0.0f;
        #pragma unroll
        for (int zz = 0; zz < N_Z; zz++)
            if (zz == zt) val = acc[zz];
        out[((size_t)(zt * N_VIEW + view)) * N_DET + det] = val;
    }
}

extern "C" void kernel_launch(void* const* d_in, const int* in_sizes, int n_in,
                              void* d_out, int out_size, void* d_ws, size_t ws_size,
                              hipStream_t stream) {
    const float* vol = (const float*)d_in[0];
    float* out = (float*)d_out;
    (void)in_sizes; (void)n_in; (void)out_size;

    const size_t need = (size_t)ZB * PV_ZSTRIDE * sizeof(unsigned);   // ~4.25 MB
    if (ws_size >= need) {
        unsigned* pv = (unsigned*)d_ws;
        for (int p = 0; p < 2; p++) {
            pad_kernel<<<dim3(ZB * PV_ROWS), dim3(256), 0, stream>>>(vol, pv, p * ZB);
            proj_kernel<<<dim3((N_VIEW / NV) * (N_DET / DG)), dim3(256), 0, stream>>>(pv, out, p * ZB);
        }
    } else {
        proj_fallback<<<dim3(N_VIEW * 8), dim3(256), 0, stream>>>(vol, out);
    }
}

// Round 7
// 748.647 us; speedup vs baseline: 3.8782x; 1.2862x over previous
//
#include <hip/hip_runtime.h>
#include <hip/hip_fp16.h>
#include <math.h>

#define N_IMG  512
#define N_Z    8
#define N_VIEW 360
#define N_DET  512
#define N_S    512
#define SLICE  (N_IMG * N_IMG)

// ---- fast path config ----
// Padded fp16 vertical-pair volume in ws:
//   PV[zz][r][c] = half2( P(r-2, c-2), P(r-1, c-2) ),  P = vol zero-padded.
// r in [0,514] covers pair-row civ in [-2,512]; c in [0,515] covers col in [-2,513].
#define PV_ROWS    515
#define PV_PITCH   516
#define PV_ZSTRIDE (PV_ROWS * PV_PITCH)   // u32 units
#define ZB 4          // z slices per pass (2 passes)
#define NV 4          // views per block (one per wave)
#define DG 32         // detectors per block
#define SC 32         // s samples per chunk
#define NCHUNK (N_S / SC)
#define ST 68         // LDS row stride in u32 (68 mod 32 == 4 -> conflict-free map)
#define ROWS_MAX 60   // window rows bound (proven <= 57)

__global__ __launch_bounds__(256) void pad_kernel(const float* __restrict__ vol,
                                                  unsigned* __restrict__ pv, int zbase) {
    const int zr = blockIdx.x;                  // 0 .. ZB*PV_ROWS-1
    const int zz = zr / PV_ROWS;
    const int r  = zr - zz * PV_ROWS;
    const float* __restrict__ img = vol + (size_t)(zbase + zz) * SLICE;
    unsigned* __restrict__ dst = pv + (size_t)zz * PV_ZSTRIDE + (size_t)r * PV_PITCH;
    const int y0 = r - 2, y1 = r - 1;
    const bool y0ok = (unsigned)y0 < (unsigned)N_IMG;
    const bool y1ok = (unsigned)y1 < (unsigned)N_IMG;
    for (int c = threadIdx.x; c < PV_PITCH; c += 256) {
        const int x = c - 2;
        const bool xok = (unsigned)x < (unsigned)N_IMG;
        const float v0 = (y0ok && xok) ? img[y0 * N_IMG + x] : 0.0f;
        const float v1 = (y1ok && xok) ? img[y1 * N_IMG + x] : 0.0f;
        __half2 h;
        h.x = __float2half(v0);
        h.y = __float2half(v1);
        dst[c] = *reinterpret_cast<unsigned*>(&h);
    }
}

// Block: 4 views (one per wave) x 32 dets x full s. Lane = 8 dets x 8 s-phases.
// Per chunk: union window over the 4 views staged once per z (fp16 vpairs);
// gather = ONE ds_read2_b32 per bilinear sample. Clamp+pad => cval=0 exact.
// launch_bounds(256,2): VGPR cap 256 -- the per-chunk sample cache (~110 live
// regs) MUST stay in registers; (256,4) capped at 64 and spilled ~180MB/dispatch
// to scratch (Round-6 counters: WRITE_SIZE 180MB, VALUBusy 33%).
__global__ __launch_bounds__(256, 2) void proj_kernel(const unsigned* __restrict__ pv,
                                                      float* __restrict__ out, int zbase) {
    __shared__ unsigned sm[ROWS_MAX * ST];

    const int g    = blockIdx.x >> 4;          // view group 0..89
    const int dg   = blockIdx.x & 15;          // det group 0..15
    const int tid  = threadIdx.x;
    const int wvid = tid >> 6;                 // wave -> view
    const int lane = tid & 63;
    const int kp   = lane & 7;                 // s-phase
    const int tl   = lane >> 3;                // det-lane 0..7
    const int view = g * NV + wvid;

    const float KTH = (float)(M_PI / 360.0);
    float c0, s0, c1, s1, c2, s2, c3, s3;
    sincosf((float)(g * 4 + 0) * KTH, &s0, &c0);
    sincosf((float)(g * 4 + 1) * KTH, &s1, &c1);
    sincosf((float)(g * 4 + 2) * KTH, &s2, &c2);
    sincosf((float)(g * 4 + 3) * KTH, &s3, &c3);
    const float c_my = (wvid == 0) ? c0 : (wvid == 1) ? c1 : (wvid == 2) ? c2 : c3;
    const float s_my = (wvid == 0) ? s0 : (wvid == 1) ? s1 : (wvid == 2) ? s2 : s3;

    const float t_base = (float)(dg * DG) - 255.5f;
    float buv[4], bvv[4];
    #pragma unroll
    for (int dd = 0; dd < 4; dd++) {
        const float tt = t_base + (float)(dd * 8 + tl);
        buv[dd] = fmaf(-s_my, tt, 255.5f);     // u = c*s + buv
        bvv[dd] = fmaf( c_my, tt, 255.5f);     // v = si*s + bvv
    }

    float acc[4][ZB];
    #pragma unroll
    for (int dd = 0; dd < 4; dd++)
        #pragma unroll
        for (int zz = 0; zz < ZB; zz++) acc[dd][zz] = 0.0f;

    for (int ck = 0; ck < NCHUNK; ++ck) {
        const float sA = (float)(ck * SC) - 255.5f;
        const float sB = sA + (float)(SC - 1);
        const float tA = t_base, tB = t_base + (float)(DG - 1);

        // Union bbox over the 4 views (separable corner min/max).
        float umin = 1e30f, umax = -1e30f, vmin = 1e30f, vmax = -1e30f;
        #pragma unroll
        for (int i = 0; i < 4; i++) {
            const float ci = (i == 0) ? c0 : (i == 1) ? c1 : (i == 2) ? c2 : c3;
            const float si = (i == 0) ? s0 : (i == 1) ? s1 : (i == 2) ? s2 : s3;
            const float ua = ci * sA, ub = ci * sB;
            const float uc = -si * tA, ud = -si * tB;
            umin = fminf(umin, fminf(ua, ub) + fminf(uc, ud));
            umax = fmaxf(umax, fmaxf(ua, ub) + fmaxf(uc, ud));
            const float va = si * sA, vb = si * sB;
            const float vc = ci * tA, vd = ci * tB;
            vmin = fminf(vmin, fminf(va, vb) + fminf(vc, vd));
            vmax = fmaxf(vmax, fmaxf(va, vb) + fmaxf(vc, vd));
        }
        umin += 255.5f; umax += 255.5f; vmin += 255.5f; vmax += 255.5f;

        const int u0   = max((int)floorf(umin) - 1, -2);
        const int uend = min((int)floorf(umax) + 2, 513);
        const int v0   = max((int)floorf(vmin) - 1, -2);
        const int vend = min((int)floorf(vmax) + 1, 512);
        if (uend < u0 || vend < v0) continue;          // block-uniform
        const int WU = min(uend - u0 + 1, ST);
        const int WV = min(vend - v0 + 1, ROWS_MAX);

        // Per-thread sample offsets/weights (cached in regs, shared across z).
        int   offs[4][4];
        float wua[4][4], wva[4][4];
        bool  act[4];
        #pragma unroll
        for (int dd = 0; dd < 4; dd++) {
            const float uA = fmaf(c_my, sA, buv[dd]), uB = fmaf(c_my, sB, buv[dd]);
            const float vA = fmaf(s_my, sA, bvv[dd]), vB = fmaf(s_my, sB, bvv[dd]);
            const float ulo = fminf(uA, uB), uhi = fmaxf(uA, uB);
            const float vlo = fminf(vA, vB), vhi = fmaxf(vA, vB);
            act[dd] = (uhi > -1.0f) && (ulo < 512.0f) && (vhi > -1.0f) && (vlo < 512.0f);
            if (act[dd]) {
                #pragma unroll
                for (int ks = 0; ks < 4; ks++) {
                    const float s = sA + (float)(ks * 8 + kp);
                    const float u = fmaf(c_my, s, buv[dd]);
                    const float v = fmaf(s_my, s, bvv[dd]);
                    const float fu = floorf(u), fv = floorf(v);
                    wua[dd][ks] = u - fu;
                    wva[dd][ks] = v - fv;
                    const int ciu = min(max((int)fu, -2), 512);
                    const int civ = min(max((int)fv, -2), 512);
                    offs[dd][ks] = (civ - v0) * ST + (ciu - u0);
                }
            }
        }

        #pragma unroll
        for (int zz = 0; zz < ZB; zz++) {
            __syncthreads();    // previous gather done before overwrite
            const unsigned* __restrict__ src = pv + (size_t)zz * PV_ZSTRIDE
                                             + (size_t)(v0 + 2) * PV_PITCH + (u0 + 2);
            if (lane < WU)
                for (int r = wvid; r < WV; r += 4)
                    sm[r * ST + lane] = src[r * PV_PITCH + lane];
            __syncthreads();
            #pragma unroll
            for (int dd = 0; dd < 4; dd++) {
                if (act[dd]) {
                    #pragma unroll
                    for (int ks = 0; ks < 4; ks++) {
                        const int o = offs[dd][ks];
                        const unsigned p0 = sm[o], p1 = sm[o + 1];
                        const __half2 h0 = *reinterpret_cast<const __half2*>(&p0);
                        const __half2 h1 = *reinterpret_cast<const __half2*>(&p1);
                        const float2 f0 = __half22float2(h0);  // x: row civ, y: row civ+1
                        const float2 f1 = __half22float2(h1);
                        const float wu = wua[dd][ks], wv = wva[dd][ks];
                        const float top = fmaf(wu, f1.x - f0.x, f0.x);
                        const float bot = fmaf(wu, f1.y - f0.y, f0.y);
                        acc[dd][zz] = fmaf(wv, bot - top, acc[dd][zz] + top);
                    }
                }
            }
        }
    }

    // Reduce the 8 s-phases; lanes kp<ZB write z = zbase+kp.
    #pragma unroll
    for (int dd = 0; dd < 4; dd++) {
        #pragma unroll
        for (int zz = 0; zz < ZB; zz++) {
            float a = acc[dd][zz];
            a += __shfl_xor(a, 1);
            a += __shfl_xor(a, 2);
            a += __shfl_xor(a, 4);
            acc[dd][zz] = a;
        }
        if (kp < ZB) {
            float val = acc[dd][0];
            if (kp == 1) val = acc[dd][1];
            else if (kp == 2) val = acc[dd][2];
            else if (kp == 3) val = acc[dd][3];
            const int det = dg * DG + dd * 8 + tl;
            out[((size_t)((zbase + kp) * N_VIEW + view)) * N_DET + det] = val;
        }
    }
}

// ---------------- fallback (Round-5 kernel, no ws needed) ----------------
#define FDG 64
#define FSC 32
#define FNC (N_S / FSC)
#define FROWS 76
#define FSTR  81

__global__ __launch_bounds__(256) void proj_fallback(const float* __restrict__ vol,
                                                     float* __restrict__ out) {
    __shared__ float sm[FROWS * FSTR];
    const int bid  = blockIdx.x;
    const int view = bid >> 3;
    const int dg   = bid & 7;
    const int tid  = threadIdx.x;
    const int lane = tid & 63;
    const int wvid = tid >> 6;
    const int kp   = lane & 3;
    const int tl   = lane >> 2;
    const int det  = dg * FDG + wvid * 16 + tl;

    const float theta = (float)view * (float)(M_PI / 360.0);
    float si, c;
    sincosf(theta, &si, &c);
    const float t  = (float)det - 255.5f;
    const float bu = fmaf(-si, t, 255.5f);
    const float bv = fmaf( c,  t, 255.5f);

    float lo = -1e30f, hi = 1e30f;
    if (fabsf(c) > 1e-7f) {
        float a = (-1.0f - bu) / c, b = (512.0f - bu) / c;
        lo = fmaxf(lo, fminf(a, b)); hi = fminf(hi, fmaxf(a, b));
    } else if (bu <= -1.0f || bu >= 512.0f) { lo = 1e30f; hi = -1e30f; }
    if (fabsf(si) > 1e-7f) {
        float a = (-1.0f - bv) / si, b = (512.0f - bv) / si;
        lo = fmaxf(lo, fminf(a, b)); hi = fminf(hi, fmaxf(a, b));
    } else if (bv <= -1.0f || bv >= 512.0f) { lo = 1e30f; hi = -1e30f; }
    int klo = 0, khi = -1;
    if (hi >= lo) {
        klo = max(0, (int)floorf(lo + 255.5f) - 1);
        khi = min(N_S - 1, (int)ceilf(hi + 255.5f) + 1);
    }
    const float tA = (float)(dg * FDG) - 255.5f;
    const float tB = tA + (float)(FDG - 1);

    float acc[N_Z];
    #pragma unroll
    for (int z = 0; z < N_Z; z++) acc[z] = 0.0f;

    for (int ck = 0; ck < FNC; ++ck) {
        const int kbase = ck * FSC;
        const float sA = -255.5f + (float)kbase;
        const float sB = sA + (float)(FSC - 1);
        const float buA = fmaf(-si, tA, 255.5f), buB = fmaf(-si, tB, 255.5f);
        const float bvA = fmaf( c,  tA, 255.5f), bvB = fmaf( c,  tB, 255.5f);
        const float u00 = fmaf(c, sA, buA), u01 = fmaf(c, sB, buA);
        const float u10 = fmaf(c, sA, buB), u11 = fmaf(c, sB, buB);
        const float v00 = fmaf(si, sA, bvA), v01 = fmaf(si, sB, bvA);
        const float v10 = fmaf(si, sA, bvB), v11 = fmaf(si, sB, bvB);
        const float umin = fminf(fminf(u00, u01), fminf(u10, u11));
        const float umax = fmaxf(fmaxf(u00, u01), fmaxf(u10, u11));
        const float vmin = fminf(fminf(v00, v01), fminf(v10, v11));
        const float vmax = fmaxf(fmaxf(v00, v01), fmaxf(v10, v11));
        const int u0c = (int)floorf(umin) - 1;
        const int v0c = (int)floorf(vmin) - 1;
        int WU = (int)floorf(umax) - u0c + 2;
        int WV = (int)floorf(vmax) - v0c + 2;
        WU = min(WU, FSTR - 1); WV = min(WV, FROWS);
        if (u0c >= N_IMG || v0c >= N_IMG || u0c + WU <= 0 || v0c + WV <= 0) continue;
        const bool active = (klo <= kbase + FSC - 1) && (khi >= kbase);
        int offs[8]; float wus[8], wvs[8];
        if (active) {
            #pragma unroll
            for (int j = 0; j < 8; j++) {
                const int k = kbase + j * 4 + kp;
                const float s = -255.5f + (float)k;
                const float u = fmaf(c, s, bu), v = fmaf(si, s, bv);
                const float fu = floorf(u), fv = floorf(v);
                wus[j] = u - fu; wvs[j] = v - fv;
                offs[j] = ((int)fv - v0c) * FSTR + ((int)fu - u0c);
            }
        }
        const int cnt = __syncthreads_count(active ? 1 : 0);
        if (cnt == 0) continue;
        #pragma unroll
        for (int z = 0; z < N_Z; ++z) {
            const float* __restrict__ img = vol + (size_t)z * SLICE;
            for (int j = wvid; j < WV; j += 4) {
                const int r = v0c + j;
                const bool rok = (unsigned)r < (unsigned)N_IMG;
                float* dstrow = &sm[j * FSTR];
                if (lane < WU) {
                    const int cc = u0c + lane;
                    float vl = 0.0f;
                    if (rok && (unsigned)cc < (unsigned)N_IMG) vl = img[r * N_IMG + cc];
                    dstrow[lane] = vl;
                }
                if (lane < WU - 64) {
                    const int cc = u0c + 64 + lane;
                    float vl = 0.0f;
                    if (rok && (unsigned)cc < (unsigned)N_IMG) vl = img[r * N_IMG + cc];
                    dstrow[64 + lane] = vl;
                }
            }
            __syncthreads();
            if (active) {
                #pragma unroll
                for (int j = 0; j < 8; j++) {
                    const int o = offs[j];
                    const float a00 = sm[o], a01 = sm[o + 1];
                    const float a10 = sm[o + FSTR], a11 = sm[o + FSTR + 1];
                    const float wu = wus[j], wv2 = wvs[j];
                    const float top = fmaf(wu, a01 - a00, a00);
                    const float bot = fmaf(wu, a11 - a10, a10);
                    acc[z] = fmaf(wv2, bot - top, acc[z] + top);
                }
            }
            __syncthreads();
        }
    }
    #pragma unroll
    for (int z = 0; z < N_Z; z++) {
        acc[z] += __shfl_xor(acc[z], 1);
        acc[z] += __shfl_xor(acc[z], 2);
    }
    #pragma unroll
    for (int j = 0; j < 2; j++) {
        const int zt = kp * 2 + j;
        float val = 0.0f;
        #pragma unroll
        for (int zz = 0; zz < N_Z; zz++)
            if (zz == zt) val = acc[zz];
        out[((size_t)(zt * N_VIEW + view)) * N_DET + det] = val;
    }
}

extern "C" void kernel_launch(void* const* d_in, const int* in_sizes, int n_in,
                              void* d_out, int out_size, void* d_ws, size_t ws_size,
                              hipStream_t stream) {
    const float* vol = (const float*)d_in[0];
    float* out = (float*)d_out;
    (void)in_sizes; (void)n_in; (void)out_size;

    const size_t need = (size_t)ZB * PV_ZSTRIDE * sizeof(unsigned);   // ~4.25 MB
    if (ws_size >= need) {
        unsigned* pv = (unsigned*)d_ws;
        for (int p = 0; p < 2; p++) {
            pad_kernel<<<dim3(ZB * PV_ROWS), dim3(256), 0, stream>>>(vol, pv, p * ZB);
            proj_kernel<<<dim3((N_VIEW / NV) * (N_DET / DG)), dim3(256), 0, stream>>>(pv, out, p * ZB);
        }
    } else {
        proj_fallback<<<dim3(N_VIEW * 8), dim3(256), 0, stream>>>(vol, out);
    }
}

// Round 8
// 417.300 us; speedup vs baseline: 6.9576x; 1.7940x over previous
//
#include <hip/hip_runtime.h>
#include <hip/hip_fp16.h>
#include <math.h>
#include <string.h>

#define N_IMG  512
#define N_Z    8
#define N_VIEW 360
#define N_DET  512
#define N_S    512
#define SLICE  (N_IMG * N_IMG)

// Padded fp16 vertical-pair volume in ws:
//   PV[zz][r][c] = half2( P(r-2, c-2), P(r-1, c-2) ),  P = vol zero-padded.
#define PV_ROWS    515
#define PV_PITCH   516
#define PV_ZSTRIDE (PV_ROWS * PV_PITCH)   // u32 units
#define ZB 4          // z slices per pass (2 passes)
#define NV 4          // views per block (one per wave)
#define DG 32         // detectors per block
#define SC 32         // s samples per chunk
#define NCHUNK (N_S / SC)
#define ST 68         // LDS row stride in u32
#define ROWS_MAX 60   // window rows bound (proven <= 57); cols <= 57 < 64 too
#define NRPT 15       // rows staged per wave (ceil(60/4))

typedef _Float16 half2v __attribute__((ext_vector_type(2)));

__global__ __launch_bounds__(256) void pad_kernel(const float* __restrict__ vol,
                                                  unsigned* __restrict__ pv, int zbase) {
    const int zr = blockIdx.x;                  // 0 .. ZB*PV_ROWS-1
    const int zz = zr / PV_ROWS;
    const int r  = zr - zz * PV_ROWS;
    const float* __restrict__ img = vol + (size_t)(zbase + zz) * SLICE;
    unsigned* __restrict__ dst = pv + (size_t)zz * PV_ZSTRIDE + (size_t)r * PV_PITCH;
    const int y0 = r - 2, y1 = r - 1;
    const bool y0ok = (unsigned)y0 < (unsigned)N_IMG;
    const bool y1ok = (unsigned)y1 < (unsigned)N_IMG;
    for (int c = threadIdx.x; c < PV_PITCH; c += 256) {
        const int x = c - 2;
        const bool xok = (unsigned)x < (unsigned)N_IMG;
        const float v0 = (y0ok && xok) ? img[y0 * N_IMG + x] : 0.0f;
        const float v1 = (y1ok && xok) ? img[y1 * N_IMG + x] : 0.0f;
        __half2 h;
        h.x = __float2half(v0);
        h.y = __float2half(v1);
        dst[c] = *reinterpret_cast<unsigned*>(&h);
    }
}

// Staging: batched predicated loads (all in flight, one wait) then LDS writes.
#define STAGE_LOAD(ZZ, BUF)                                                  \
    {                                                                        \
        const unsigned* __restrict__ srcz = src0 + (size_t)(ZZ) * PV_ZSTRIDE;\
        _Pragma("unroll")                                                    \
        for (int i = 0; i < NRPT; i++) {                                     \
            const int r = wvid + i * 4;                                      \
            BUF[i] = (r < WV) ? srcz[(size_t)r * PV_PITCH + lane] : 0u;      \
        }                                                                    \
    }
#define STAGE_WRITE(BUF)                                                     \
    {                                                                        \
        _Pragma("unroll")                                                    \
        for (int i = 0; i < NRPT; i++) {                                     \
            const int r = wvid + i * 4;                                      \
            if (r < WV) sm[r * ST + lane] = BUF[i];                          \
        }                                                                    \
    }
// Sample: pk_fma u-lerp in fp16, dot2 v-combine accumulating in f32.
#define GATHER(ZZ)                                                           \
    {                                                                        \
        _Pragma("unroll")                                                    \
        for (int dd = 0; dd < 4; dd++) if (act[dd]) {                        \
            _Pragma("unroll")                                                \
            for (int ks = 0; ks < 4; ks++) {                                 \
                const int o = offs[dd][ks];                                  \
                const unsigned p0 = sm[o], p1 = sm[o + 1];                   \
                half2v h0 = __builtin_bit_cast(half2v, p0);                  \
                half2v h1 = __builtin_bit_cast(half2v, p1);                  \
                half2v rr = h0 + wu2a[dd][ks] * (h1 - h0);                   \
                acc[dd][ZZ] = __builtin_amdgcn_fdot2(rr, wv2a[dd][ks],       \
                                                     acc[dd][ZZ], false);    \
            }                                                                \
        }                                                                    \
    }

// Block: 4 views (one per wave) x 32 dets x full s. Lane = 8 dets x 8 s-phases.
// launch_bounds(256,2): VGPR cap 256 -- per-chunk sample cache must stay in regs
// ((256,4) capped at 64 and spilled 180MB/dispatch -- Round-6 counters).
__global__ __launch_bounds__(256, 2) void proj_kernel(const unsigned* __restrict__ pv,
                                                      float* __restrict__ out, int zbase) {
    __shared__ unsigned sm[ROWS_MAX * ST];

    const int g    = blockIdx.x >> 4;          // view group 0..89
    const int dg   = blockIdx.x & 15;          // det group 0..15
    const int tid  = threadIdx.x;
    const int wvid = tid >> 6;                 // wave -> view
    const int lane = tid & 63;
    const int kp   = lane & 7;                 // s-phase
    const int tl   = lane >> 3;                // det-lane 0..7
    const int view = g * NV + wvid;

    const float KTH = (float)(M_PI / 360.0);
    float c0, s0, c1, s1, c2, s2, c3, s3;
    sincosf((float)(g * 4 + 0) * KTH, &s0, &c0);
    sincosf((float)(g * 4 + 1) * KTH, &s1, &c1);
    sincosf((float)(g * 4 + 2) * KTH, &s2, &c2);
    sincosf((float)(g * 4 + 3) * KTH, &s3, &c3);
    const float c_my = (wvid == 0) ? c0 : (wvid == 1) ? c1 : (wvid == 2) ? c2 : c3;
    const float s_my = (wvid == 0) ? s0 : (wvid == 1) ? s1 : (wvid == 2) ? s2 : s3;

    const float t_base = (float)(dg * DG) - 255.5f;
    float buv[4], bvv[4];
    #pragma unroll
    for (int dd = 0; dd < 4; dd++) {
        const float tt = t_base + (float)(dd * 8 + tl);
        buv[dd] = fmaf(-s_my, tt, 255.5f);     // u = c*s + buv
        bvv[dd] = fmaf( c_my, tt, 255.5f);     // v = si*s + bvv
    }

    float acc[4][ZB];
    #pragma unroll
    for (int dd = 0; dd < 4; dd++)
        #pragma unroll
        for (int zz = 0; zz < ZB; zz++) acc[dd][zz] = 0.0f;

    for (int ck = 0; ck < NCHUNK; ++ck) {
        const float sA = (float)(ck * SC) - 255.5f;
        const float sB = sA + (float)(SC - 1);
        const float tA = t_base, tB = t_base + (float)(DG - 1);

        // Union bbox over the 4 views (separable corner min/max).
        float umin = 1e30f, umax = -1e30f, vmin = 1e30f, vmax = -1e30f;
        #pragma unroll
        for (int i = 0; i < 4; i++) {
            const float ci = (i == 0) ? c0 : (i == 1) ? c1 : (i == 2) ? c2 : c3;
            const float si = (i == 0) ? s0 : (i == 1) ? s1 : (i == 2) ? s2 : s3;
            const float ua = ci * sA, ub = ci * sB;
            const float uc = -si * tA, ud = -si * tB;
            umin = fminf(umin, fminf(ua, ub) + fminf(uc, ud));
            umax = fmaxf(umax, fmaxf(ua, ub) + fmaxf(uc, ud));
            const float va = si * sA, vb = si * sB;
            const float vc = ci * tA, vd = ci * tB;
            vmin = fminf(vmin, fminf(va, vb) + fminf(vc, vd));
            vmax = fmaxf(vmax, fmaxf(va, vb) + fmaxf(vc, vd));
        }
        umin += 255.5f; umax += 255.5f; vmin += 255.5f; vmax += 255.5f;

        const int u0   = max((int)floorf(umin) - 1, -2);
        const int uend = min((int)floorf(umax) + 2, 513);
        const int v0   = max((int)floorf(vmin) - 1, -2);
        const int vend = min((int)floorf(vmax) + 1, 512);
        if (uend < u0 || vend < v0) continue;          // block-uniform
        const int WU = min(uend - u0 + 1, 64);         // proven <= 57
        const int WV = min(vend - v0 + 1, ROWS_MAX);   // proven <= 57
        (void)WU;

        // Per-thread sample offsets + packed fp16 weights (shared across z).
        int    offs[4][4];
        half2v wu2a[4][4], wv2a[4][4];
        bool   act[4];
        #pragma unroll
        for (int dd = 0; dd < 4; dd++) {
            const float uA = fmaf(c_my, sA, buv[dd]), uB = fmaf(c_my, sB, buv[dd]);
            const float vA = fmaf(s_my, sA, bvv[dd]), vB = fmaf(s_my, sB, bvv[dd]);
            const float ulo = fminf(uA, uB), uhi = fmaxf(uA, uB);
            const float vlo = fminf(vA, vB), vhi = fmaxf(vA, vB);
            act[dd] = (uhi > -1.0f) && (ulo < 512.0f) && (vhi > -1.0f) && (vlo < 512.0f);
            if (act[dd]) {
                #pragma unroll
                for (int ks = 0; ks < 4; ks++) {
                    const float s = sA + (float)(ks * 8 + kp);
                    const float u = fmaf(c_my, s, buv[dd]);
                    const float v = fmaf(s_my, s, bvv[dd]);
                    const float fu = floorf(u), fv = floorf(v);
                    const _Float16 wuh = (_Float16)(u - fu);
                    const _Float16 wvh = (_Float16)(v - fv);
                    wu2a[dd][ks] = (half2v){wuh, wuh};
                    wv2a[dd][ks] = (half2v){(_Float16)((_Float16)1.0f - wvh), wvh};
                    const int ciu = min(max((int)fu, -2), 512);
                    const int civ = min(max((int)fv, -2), 512);
                    offs[dd][ks] = (civ - v0) * ST + (ciu - u0);
                }
            }
        }

        const unsigned* __restrict__ src0 = pv + (size_t)(v0 + 2) * PV_PITCH + (u0 + 2);
        unsigned bufA[NRPT], bufB[NRPT];

        STAGE_LOAD(0, bufA);
        // zz = 0
        __syncthreads();                 // prev chunk's gather done
        STAGE_WRITE(bufA);
        __syncthreads();
        STAGE_LOAD(1, bufB);             // fly during gather 0
        GATHER(0);
        // zz = 1
        __syncthreads();
        STAGE_WRITE(bufB);
        __syncthreads();
        STAGE_LOAD(2, bufA);
        GATHER(1);
        // zz = 2
        __syncthreads();
        STAGE_WRITE(bufA);
        __syncthreads();
        STAGE_LOAD(3, bufB);
        GATHER(2);
        // zz = 3
        __syncthreads();
        STAGE_WRITE(bufB);
        __syncthreads();
        GATHER(3);
    }

    // Reduce the 8 s-phases; lanes kp<ZB write z = zbase+kp.
    #pragma unroll
    for (int dd = 0; dd < 4; dd++) {
        #pragma unroll
        for (int zz = 0; zz < ZB; zz++) {
            float a = acc[dd][zz];
            a += __shfl_xor(a, 1);
            a += __shfl_xor(a, 2);
            a += __shfl_xor(a, 4);
            acc[dd][zz] = a;
        }
        if (kp < ZB) {
            float val = acc[dd][0];
            if (kp == 1) val = acc[dd][1];
            else if (kp == 2) val = acc[dd][2];
            else if (kp == 3) val = acc[dd][3];
            const int det = dg * DG + dd * 8 + tl;
            out[((size_t)((zbase + kp) * N_VIEW + view)) * N_DET + det] = val;
        }
    }
}

// ---------------- fallback (Round-5 kernel, no ws needed) ----------------
#define FDG 64
#define FSC 32
#define FNC (N_S / FSC)
#define FROWS 76
#define FSTR  81

__global__ __launch_bounds__(256) void proj_fallback(const float* __restrict__ vol,
                                                     float* __restrict__ out) {
    __shared__ float sm[FROWS * FSTR];
    const int bid  = blockIdx.x;
    const int view = bid >> 3;
    const int dg   = bid & 7;
    const int tid  = threadIdx.x;
    const int lane = tid & 63;
    const int wvid = tid >> 6;
    const int kp   = lane & 3;
    const int tl   = lane >> 2;
    const int det  = dg * FDG + wvid * 16 + tl;

    const float theta = (float)view * (float)(M_PI / 360.0);
    float si, c;
    sincosf(theta, &si, &c);
    const float t  = (float)det - 255.5f;
    const float bu = fmaf(-si, t, 255.5f);
    const float bv = fmaf( c,  t, 255.5f);

    float lo = -1e30f, hi = 1e30f;
    if (fabsf(c) > 1e-7f) {
        float a = (-1.0f - bu) / c, b = (512.0f - bu) / c;
        lo = fmaxf(lo, fminf(a, b)); hi = fminf(hi, fmaxf(a, b));
    } else if (bu <= -1.0f || bu >= 512.0f) { lo = 1e30f; hi = -1e30f; }
    if (fabsf(si) > 1e-7f) {
        float a = (-1.0f - bv) / si, b = (512.0f - bv) / si;
        lo = fmaxf(lo, fminf(a, b)); hi = fminf(hi, fmaxf(a, b));
    } else if (bv <= -1.0f || bv >= 512.0f) { lo = 1e30f; hi = -1e30f; }
    int klo = 0, khi = -1;
    if (hi >= lo) {
        klo = max(0, (int)floorf(lo + 255.5f) - 1);
        khi = min(N_S - 1, (int)ceilf(hi + 255.5f) + 1);
    }
    const float tA = (float)(dg * FDG) - 255.5f;
    const float tB = tA + (float)(FDG - 1);

    float acc[N_Z];
    #pragma unroll
    for (int z = 0; z < N_Z; z++) acc[z] = 0.0f;

    for (int ck = 0; ck < FNC; ++ck) {
        const int kbase = ck * FSC;
        const float sA = -255.5f + (float)kbase;
        const float sB = sA + (float)(FSC - 1);
        const float buA = fmaf(-si, tA, 255.5f), buB = fmaf(-si, tB, 255.5f);
        const float bvA = fmaf( c,  tA, 255.5f), bvB = fmaf( c,  tB, 255.5f);
        const float u00 = fmaf(c, sA, buA), u01 = fmaf(c, sB, buA);
        const float u10 = fmaf(c, sA, buB), u11 = fmaf(c, sB, buB);
        const float v00 = fmaf(si, sA, bvA), v01 = fmaf(si, sB, bvA);
        const float v10 = fmaf(si, sA, bvB), v11 = fmaf(si, sB, bvB);
        const float umin = fminf(fminf(u00, u01), fminf(u10, u11));
        const float umax = fmaxf(fmaxf(u00, u01), fmaxf(u10, u11));
        const float vmin = fminf(fminf(v00, v01), fminf(v10, v11));
        const float vmax = fmaxf(fmaxf(v00, v01), fmaxf(v10, v11));
        const int u0c = (int)floorf(umin) - 1;
        const int v0c = (int)floorf(vmin) - 1;
        int WU = (int)floorf(umax) - u0c + 2;
        int WV = (int)floorf(vmax) - v0c + 2;
        WU = min(WU, FSTR - 1); WV = min(WV, FROWS);
        if (u0c >= N_IMG || v0c >= N_IMG || u0c + WU <= 0 || v0c + WV <= 0) continue;
        const bool active = (klo <= kbase + FSC - 1) && (khi >= kbase);
        int offs[8]; float wus[8], wvs[8];
        if (active) {
            #pragma unroll
            for (int j = 0; j < 8; j++) {
                const int k = kbase + j * 4 + kp;
                const float s = -255.5f + (float)k;
                const float u = fmaf(c, s, bu), v = fmaf(si, s, bv);
                const float fu = floorf(u), fv = floorf(v);
                wus[j] = u - fu; wvs[j] = v - fv;
                offs[j] = ((int)fv - v0c) * FSTR + ((int)fu - u0c);
            }
        }
        const int cnt = __syncthreads_count(active ? 1 : 0);
        if (cnt == 0) continue;
        #pragma unroll
        for (int z = 0; z < N_Z; ++z) {
            const float* __restrict__ img = vol + (size_t)z * SLICE;
            for (int j = wvid; j < WV; j += 4) {
                const int r = v0c + j;
                const bool rok = (unsigned)r < (unsigned)N_IMG;
                float* dstrow = &sm[j * FSTR];
                if (lane < WU) {
                    const int cc = u0c + lane;
                    float vl = 0.0f;
                    if (rok && (unsigned)cc < (unsigned)N_IMG) vl = img[r * N_IMG + cc];
                    dstrow[lane] = vl;
                }
                if (lane < WU - 64) {
                    const int cc = u0c + 64 + lane;
                    float vl = 0.0f;
                    if (rok && (unsigned)cc < (unsigned)N_IMG) vl = img[r * N_IMG + cc];
                    dstrow[64 + lane] = vl;
                }
            }
            __syncthreads();
            if (active) {
                #pragma unroll
                for (int j = 0; j < 8; j++) {
                    const int o = offs[j];
                    const float a00 = sm[o], a01 = sm[o + 1];
                    const float a10 = sm[o + FSTR], a11 = sm[o + FSTR + 1];
                    const float wu = wus[j], wv2 = wvs[j];
                    const float top = fmaf(wu, a01 - a00, a00);
                    const float bot = fmaf(wu, a11 - a10, a10);
                    acc[z] = fmaf(wv2, bot - top, acc[z] + top);
                }
            }
            __syncthreads();
        }
    }
    #pragma unroll
    for (int z = 0; z < N_Z; z++) {
        acc[z] += __shfl_xor(acc[z], 1);
        acc[z] += __shfl_xor(acc[z], 2);
    }
    #pragma unroll
    for (int j = 0; j < 2; j++) {
        const int zt = kp * 2 + j;
        float val = 0.0f;
        #pragma unroll
        for (int zz = 0; zz < N_Z; zz++)
            if (zz == zt) val = acc[zz];
        out[((size_t)(zt * N_VIEW + view)) * N_DET + det] = val;
    }
}

extern "C" void kernel_launch(void* const* d_in, const int* in_sizes, int n_in,
                              void* d_out, int out_size, void* d_ws, size_t ws_size,
                              hipStream_t stream) {
    const float* vol = (const float*)d_in[0];
    float* out = (float*)d_out;
    (void)in_sizes; (void)n_in; (void)out_size;

    // +1KB slack: staging reads a full 64-lane row segment regardless of WU,
    // overrunning the pv buffer by <= 252B on the last row of the last slice.
    const size_t need = (size_t)ZB * PV_ZSTRIDE * sizeof(unsigned) + 1024;
    if (ws_size >= need) {
        unsigned* pv = (unsigned*)d_ws;
        for (int p = 0; p < 2; p++) {
            pad_kernel<<<dim3(ZB * PV_ROWS), dim3(256), 0, stream>>>(vol, pv, p * ZB);
            proj_kernel<<<dim3((N_VIEW / NV) * (N_DET / DG)), dim3(256), 0, stream>>>(pv, out, p * ZB);
        }
    } else {
        proj_fallback<<<dim3(N_VIEW * 8), dim3(256), 0, stream>>>(vol, out);
    }
}

// Round 9
// 391.356 us; speedup vs baseline: 7.4188x; 1.0663x over previous
//
#include <hip/hip_runtime.h>
#include <hip/hip_fp16.h>
#include <math.h>

#define N_IMG  512
#define N_Z    8
#define N_VIEW 360
#define N_DET  512
#define N_S    512
#define SLICE  (N_IMG * N_IMG)

// Padded fp16 z-pair/row-pair volume in ws:
//   PVI[zp][r][c].x = half2( P_{2zp}  (r-2, c-2), P_{2zp}  (r-1, c-2) )
//   PVI[zp][r][c].y = half2( P_{2zp+1}(r-2, c-2), P_{2zp+1}(r-1, c-2) )
// P = vol zero-padded. r in [0,514] covers pair-row civ in [-2,512];
// c in [0,515] covers col ciu in [-2,513].
#define PV_ROWS    515
#define PV_PITCH   516
#define PV_ZSTRIDE (PV_ROWS * PV_PITCH)   // uint2 units
#define NV 4          // views per block (one per wave)
#define DG 32         // detectors per block
#define SC 32         // s samples per chunk
#define NCHUNK (N_S / SC)
#define ST2 62        // LDS row stride in uint2 cells: 16B-aligned rows (496B),
                      // bank map (14*tl+kp)%16 exactly uniform at theta=0 and 90
#define ROWS_MAX 60   // window rows bound (proven <= 58)
#define NRPT 15       // rows staged per wave

typedef _Float16 half2v __attribute__((ext_vector_type(2)));

__device__ __forceinline__ void dma16(const uint2* g, uint2* l) {
    // async global->LDS, 16B/lane, LDS dest = wave-uniform base + lane*16
    __builtin_amdgcn_global_load_lds((const __attribute__((address_space(1))) unsigned*)g,
                                     (__attribute__((address_space(3))) unsigned*)l,
                                     16, 0, 0);
}

__global__ __launch_bounds__(256) void pad_kernel(const float* __restrict__ vol,
                                                  uint2* __restrict__ pv, int zbase) {
    const int zr = blockIdx.x;                  // 0 .. NZPG*PV_ROWS-1
    const int zp = zr / PV_ROWS;
    const int r  = zr - zp * PV_ROWS;
    const float* __restrict__ i0 = vol + (size_t)(zbase + 2 * zp) * SLICE;
    const float* __restrict__ i1 = i0 + SLICE;
    uint2* __restrict__ dst = pv + (size_t)zp * PV_ZSTRIDE + (size_t)r * PV_PITCH;
    const int y0 = r - 2, y1 = r - 1;
    const bool y0ok = (unsigned)y0 < (unsigned)N_IMG;
    const bool y1ok = (unsigned)y1 < (unsigned)N_IMG;
    for (int c = threadIdx.x; c < PV_PITCH; c += 256) {
        const int x = c - 2;
        const bool xok = (unsigned)x < (unsigned)N_IMG;
        const float e0 = (y0ok && xok) ? i0[y0 * N_IMG + x] : 0.0f;
        const float e1 = (y1ok && xok) ? i0[y1 * N_IMG + x] : 0.0f;
        const float o0 = (y0ok && xok) ? i1[y0 * N_IMG + x] : 0.0f;
        const float o1 = (y1ok && xok) ? i1[y1 * N_IMG + x] : 0.0f;
        __half2 he; he.x = __float2half(e0); he.y = __float2half(e1);
        __half2 ho; ho.x = __float2half(o0); ho.y = __float2half(o1);
        uint2 cell;
        cell.x = *reinterpret_cast<unsigned*>(&he);
        cell.y = *reinterpret_cast<unsigned*>(&ho);
        dst[c] = cell;
    }
}

// DMA a zp window into LDS: rows r (one 16B segment per lane, 2 cells/lane).
#define DMA_STAGE(ZP)                                                         \
    {                                                                         \
        const uint2* __restrict__ srcz = src0 + (size_t)(ZP) * PV_ZSTRIDE;    \
        if (lane < nseg) {                                                    \
            _Pragma("unroll")                                                 \
            for (int i = 0; i < NRPT; i++) {                                  \
                const int r = wvid + i * 4;                                   \
                if (r < WV)                                                   \
                    dma16(srcz + (size_t)r * PV_PITCH + lane * 2,             \
                          sm + r * ST2);                                      \
            }                                                                 \
        }                                                                     \
    }

// One ds_read2_b64 per sample serves the bilinear for BOTH z of the pair.
#define GATHER(ZP)                                                            \
    {                                                                         \
        _Pragma("unroll")                                                     \
        for (int dd = 0; dd < 4; dd++) if (act[dd]) {                         \
            _Pragma("unroll")                                                 \
            for (int ks = 0; ks < 4; ks++) {                                  \
                const int o = offs[dd][ks];                                   \
                const uint2 q0 = sm[o];                                       \
                const uint2 q1 = sm[o + 1];                                   \
                const half2v e0 = __builtin_bit_cast(half2v, q0.x);           \
                const half2v od0 = __builtin_bit_cast(half2v, q0.y);          \
                const half2v e1 = __builtin_bit_cast(half2v, q1.x);           \
                const half2v od1 = __builtin_bit_cast(half2v, q1.y);          \
                const half2v wu = wu2a[dd][ks];                               \
                const half2v re = e0 + wu * (e1 - e0);                        \
                const half2v ro = od0 + wu * (od1 - od0);                     \
                acc[dd][ZP][0] = __builtin_amdgcn_fdot2(re, wv2a[dd][ks],     \
                                                        acc[dd][ZP][0], false);\
                acc[dd][ZP][1] = __builtin_amdgcn_fdot2(ro, wv2a[dd][ks],     \
                                                        acc[dd][ZP][1], false);\
            }                                                                 \
        }                                                                     \
    }

// Block: 4 views (one per wave) x 32 dets x full s. Lane = 8 dets x 8 s-phases.
// launch_bounds(256,2): VGPR cap 256 -- sample cache must stay in regs (R6 lesson).
template <int NZP>
__global__ __launch_bounds__(256, 2) void proj_kernel(const uint2* __restrict__ pv,
                                                      float* __restrict__ out, int zbase) {
    __shared__ uint2 sm[ROWS_MAX * ST2];

    const int g    = blockIdx.x >> 4;          // view group 0..89
    const int dg   = blockIdx.x & 15;          // det group 0..15
    const int tid  = threadIdx.x;
    const int wvid = tid >> 6;                 // wave -> view
    const int lane = tid & 63;
    const int kp   = lane & 7;                 // s-phase
    const int tl   = lane >> 3;                // det-lane 0..7
    const int view = g * NV + wvid;

    const float KTH = (float)(M_PI / 360.0);
    float c0, s0, c1, s1, c2, s2, c3, s3;
    sincosf((float)(g * 4 + 0) * KTH, &s0, &c0);
    sincosf((float)(g * 4 + 1) * KTH, &s1, &c1);
    sincosf((float)(g * 4 + 2) * KTH, &s2, &c2);
    sincosf((float)(g * 4 + 3) * KTH, &s3, &c3);
    const float c_my = (wvid == 0) ? c0 : (wvid == 1) ? c1 : (wvid == 2) ? c2 : c3;
    const float s_my = (wvid == 0) ? s0 : (wvid == 1) ? s1 : (wvid == 2) ? s2 : s3;

    const float t_base = (float)(dg * DG) - 255.5f;
    float buv[4], bvv[4];
    #pragma unroll
    for (int dd = 0; dd < 4; dd++) {
        const float tt = t_base + (float)(dd * 8 + tl);
        buv[dd] = fmaf(-s_my, tt, 255.5f);     // u = c*s + buv
        bvv[dd] = fmaf( c_my, tt, 255.5f);     // v = si*s + bvv
    }

    float acc[4][NZP][2];
    #pragma unroll
    for (int dd = 0; dd < 4; dd++)
        #pragma unroll
        for (int zz = 0; zz < NZP; zz++) { acc[dd][zz][0] = 0.0f; acc[dd][zz][1] = 0.0f; }

    for (int ck = 0; ck < NCHUNK; ++ck) {
        const float sA = (float)(ck * SC) - 255.5f;
        const float sB = sA + (float)(SC - 1);
        const float tA = t_base, tB = t_base + (float)(DG - 1);

        // Union bbox over the 4 views (block-uniform).
        float umin = 1e30f, umax = -1e30f, vmin = 1e30f, vmax = -1e30f;
        #pragma unroll
        for (int i = 0; i < 4; i++) {
            const float ci = (i == 0) ? c0 : (i == 1) ? c1 : (i == 2) ? c2 : c3;
            const float si = (i == 0) ? s0 : (i == 1) ? s1 : (i == 2) ? s2 : s3;
            const float ua = ci * sA, ub = ci * sB;
            const float uc = -si * tA, ud = -si * tB;
            umin = fminf(umin, fminf(ua, ub) + fminf(uc, ud));
            umax = fmaxf(umax, fmaxf(ua, ub) + fmaxf(uc, ud));
            const float va = si * sA, vb = si * sB;
            const float vc = ci * tA, vd = ci * tB;
            vmin = fminf(vmin, fminf(va, vb) + fminf(vc, vd));
            vmax = fmaxf(vmax, fmaxf(va, vb) + fmaxf(vc, vd));
        }
        umin += 255.5f; umax += 255.5f; vmin += 255.5f; vmax += 255.5f;

        const int u0   = max((int)floorf(umin) - 1, -2);
        const int uend = min((int)floorf(umax) + 2, 513);
        const int v0   = max((int)floorf(vmin) - 1, -2);
        const int vend = min((int)floorf(vmax) + 1, 512);
        if (uend < u0 || vend < v0) continue;          // block-uniform
        const int WU = min(uend - u0 + 1, ST2 - 1);    // proven <= 58
        const int WV = min(vend - v0 + 1, ROWS_MAX);   // proven <= 58
        const int nseg = (WU + 1) >> 1;                // 16B segments per row

        // Per-thread sample offsets + packed fp16 weights (shared across z).
        int    offs[4][4];
        half2v wu2a[4][4], wv2a[4][4];
        bool   act[4];
        #pragma unroll
        for (int dd = 0; dd < 4; dd++) {
            const float uA = fmaf(c_my, sA, buv[dd]), uB = fmaf(c_my, sB, buv[dd]);
            const float vA = fmaf(s_my, sA, bvv[dd]), vB = fmaf(s_my, sB, bvv[dd]);
            const float ulo = fminf(uA, uB), uhi = fmaxf(uA, uB);
            const float vlo = fminf(vA, vB), vhi = fmaxf(vA, vB);
            act[dd] = (uhi > -1.0f) && (ulo < 512.0f) && (vhi > -1.0f) && (vlo < 512.0f);
            if (act[dd]) {
                #pragma unroll
                for (int ks = 0; ks < 4; ks++) {
                    const float s = sA + (float)(ks * 8 + kp);
                    const float u = fmaf(c_my, s, buv[dd]);
                    const float v = fmaf(s_my, s, bvv[dd]);
                    const float fu = floorf(u), fv = floorf(v);
                    const _Float16 wuh = (_Float16)(u - fu);
                    const _Float16 wvh = (_Float16)(v - fv);
                    wu2a[dd][ks] = (half2v){wuh, wuh};
                    wv2a[dd][ks] = (half2v){(_Float16)((_Float16)1.0f - wvh), wvh};
                    const int ciu = min(max((int)fu, -2), 512);
                    const int civ = min(max((int)fv, -2), 512);
                    offs[dd][ks] = (civ - v0) * ST2 + (ciu - u0);
                }
            }
        }

        const uint2* __restrict__ src0 = pv + (size_t)(v0 + 2) * PV_PITCH + (u0 + 2);

        #pragma unroll
        for (int zp = 0; zp < NZP; ++zp) {
            __syncthreads();                   // previous gather done
            DMA_STAGE(zp);
            asm volatile("s_waitcnt vmcnt(0)" ::: "memory");
            __syncthreads();                   // window landed for all waves
            GATHER(zp);
        }
    }

    // Reduce the 8 s-phases (kp octet); lane kp writes z = zbase + kp.
    #pragma unroll
    for (int dd = 0; dd < 4; dd++) {
        #pragma unroll
        for (int zz = 0; zz < NZP; zz++) {
            #pragma unroll
            for (int j = 0; j < 2; j++) {
                float a = acc[dd][zz][j];
                a += __shfl_xor(a, 1);
                a += __shfl_xor(a, 2);
                a += __shfl_xor(a, 4);
                acc[dd][zz][j] = a;
            }
        }
        if (kp < 2 * NZP) {
            float val = 0.0f;
            #pragma unroll
            for (int zz = 0; zz < NZP; zz++)
                #pragma unroll
                for (int j = 0; j < 2; j++)
                    if ((kp >> 1) == zz && (kp & 1) == j) val = acc[dd][zz][j];
            const int det = dg * DG + dd * 8 + tl;
            const int z = zbase + kp;
            out[((size_t)(z * N_VIEW + view)) * N_DET + det] = val;
        }
    }
}

// ---------------- fallback (Round-5 kernel, no ws needed) ----------------
#define FDG 64
#define FSC 32
#define FNC (N_S / FSC)
#define FROWS 76
#define FSTR  81

__global__ __launch_bounds__(256) void proj_fallback(const float* __restrict__ vol,
                                                     float* __restrict__ out) {
    __shared__ float sm[FROWS * FSTR];
    const int bid  = blockIdx.x;
    const int view = bid >> 3;
    const int dg   = bid & 7;
    const int tid  = threadIdx.x;
    const int lane = tid & 63;
    const int wvid = tid >> 6;
    const int kp   = lane & 3;
    const int tl   = lane >> 2;
    const int det  = dg * FDG + wvid * 16 + tl;

    const float theta = (float)view * (float)(M_PI / 360.0);
    float si, c;
    sincosf(theta, &si, &c);
    const float t  = (float)det - 255.5f;
    const float bu = fmaf(-si, t, 255.5f);
    const float bv = fmaf( c,  t, 255.5f);

    float lo = -1e30f, hi = 1e30f;
    if (fabsf(c) > 1e-7f) {
        float a = (-1.0f - bu) / c, b = (512.0f - bu) / c;
        lo = fmaxf(lo, fminf(a, b)); hi = fminf(hi, fmaxf(a, b));
    } else if (bu <= -1.0f || bu >= 512.0f) { lo = 1e30f; hi = -1e30f; }
    if (fabsf(si) > 1e-7f) {
        float a = (-1.0f - bv) / si, b = (512.0f - bv) / si;
        lo = fmaxf(lo, fminf(a, b)); hi = fminf(hi, fmaxf(a, b));
    } else if (bv <= -1.0f || bv >= 512.0f) { lo = 1e30f; hi = -1e30f; }
    int klo = 0, khi = -1;
    if (hi >= lo) {
        klo = max(0, (int)floorf(lo + 255.5f) - 1);
        khi = min(N_S - 1, (int)ceilf(hi + 255.5f) + 1);
    }
    const float tA = (float)(dg * FDG) - 255.5f;
    const float tB = tA + (float)(FDG - 1);

    float acc[N_Z];
    #pragma unroll
    for (int z = 0; z < N_Z; z++) acc[z] = 0.0f;

    for (int ck = 0; ck < FNC; ++ck) {
        const int kbase = ck * FSC;
        const float sA = -255.5f + (float)kbase;
        const float sB = sA + (float)(FSC - 1);
        const float buA = fmaf(-si, tA, 255.5f), buB = fmaf(-si, tB, 255.5f);
        const float bvA = fmaf( c,  tA, 255.5f), bvB = fmaf( c,  tB, 255.5f);
        const float u00 = fmaf(c, sA, buA), u01 = fmaf(c, sB, buA);
        const float u10 = fmaf(c, sA, buB), u11 = fmaf(c, sB, buB);
        const float v00 = fmaf(si, sA, bvA), v01 = fmaf(si, sB, bvA);
        const float v10 = fmaf(si, sA, bvB), v11 = fmaf(si, sB, bvB);
        const float umin = fminf(fminf(u00, u01), fminf(u10, u11));
        const float umax = fmaxf(fmaxf(u00, u01), fmaxf(u10, u11));
        const float vmin = fminf(fminf(v00, v01), fminf(v10, v11));
        const float vmax = fmaxf(fmaxf(v00, v01), fmaxf(v10, v11));
        const int u0c = (int)floorf(umin) - 1;
        const int v0c = (int)floorf(vmin) - 1;
        int WU = (int)floorf(umax) - u0c + 2;
        int WV = (int)floorf(vmax) - v0c + 2;
        WU = min(WU, FSTR - 1); WV = min(WV, FROWS);
        if (u0c >= N_IMG || v0c >= N_IMG || u0c + WU <= 0 || v0c + WV <= 0) continue;
        const bool active = (klo <= kbase + FSC - 1) && (khi >= kbase);
        int offs[8]; float wus[8], wvs[8];
        if (active) {
            #pragma unroll
            for (int j = 0; j < 8; j++) {
                const int k = kbase + j * 4 + kp;
                const float s = -255.5f + (float)k;
                const float u = fmaf(c, s, bu), v = fmaf(si, s, bv);
                const float fu = floorf(u), fv = floorf(v);
                wus[j] = u - fu; wvs[j] = v - fv;
                offs[j] = ((int)fv - v0c) * FSTR + ((int)fu - u0c);
            }
        }
        const int cnt = __syncthreads_count(active ? 1 : 0);
        if (cnt == 0) continue;
        #pragma unroll
        for (int z = 0; z < N_Z; ++z) {
            const float* __restrict__ img = vol + (size_t)z * SLICE;
            for (int j = wvid; j < WV; j += 4) {
                const int r = v0c + j;
                const bool rok = (unsigned)r < (unsigned)N_IMG;
                float* dstrow = &sm[j * FSTR];
                if (lane < WU) {
                    const int cc = u0c + lane;
                    float vl = 0.0f;
                    if (rok && (unsigned)cc < (unsigned)N_IMG) vl = img[r * N_IMG + cc];
                    dstrow[lane] = vl;
                }
                if (lane < WU - 64) {
                    const int cc = u0c + 64 + lane;
                    float vl = 0.0f;
                    if (rok && (unsigned)cc < (unsigned)N_IMG) vl = img[r * N_IMG + cc];
                    dstrow[64 + lane] = vl;
                }
            }
            __syncthreads();
            if (active) {
                #pragma unroll
                for (int j = 0; j < 8; j++) {
                    const int o = offs[j];
                    const float a00 = sm[o], a01 = sm[o + 1];
                    const float a10 = sm[o + FSTR], a11 = sm[o + FSTR + 1];
                    const float wu = wus[j], wv2 = wvs[j];
                    const float top = fmaf(wu, a01 - a00, a00);
                    const float bot = fmaf(wu, a11 - a10, a10);
                    acc[z] = fmaf(wv2, bot - top, acc[z] + top);
                }
            }
            __syncthreads();
        }
    }
    #pragma unroll
    for (int z = 0; z < N_Z; z++) {
        acc[z] += __shfl_xor(acc[z], 1);
        acc[z] += __shfl_xor(acc[z], 2);
    }
    #pragma unroll
    for (int j = 0; j < 2; j++) {
        const int zt = kp * 2 + j;
        float val = 0.0f;
        #pragma unroll
        for (int zz = 0; zz < N_Z; zz++)
            if (zz == zt) val = acc[zz];
        out[((size_t)(zt * N_VIEW + view)) * N_DET + det] = val;
    }
}

extern "C" void kernel_launch(void* const* d_in, const int* in_sizes, int n_in,
                              void* d_out, int out_size, void* d_ws, size_t ws_size,
                              hipStream_t stream) {
    const float* vol = (const float*)d_in[0];
    float* out = (float*)d_out;
    (void)in_sizes; (void)n_in; (void)out_size;

    // +4KB slack: row-tail DMA segments can overrun the pv buffer by < 512B.
    const size_t need4 = (size_t)4 * PV_ZSTRIDE * sizeof(uint2) + 4096;  // ~8.5 MB
    const size_t need2 = (size_t)2 * PV_ZSTRIDE * sizeof(uint2) + 4096;  // ~4.25 MB
    if (ws_size >= need4) {
        uint2* pv = (uint2*)d_ws;
        pad_kernel<<<dim3(4 * PV_ROWS), dim3(256), 0, stream>>>(vol, pv, 0);
        proj_kernel<4><<<dim3((N_VIEW / NV) * (N_DET / DG)), dim3(256), 0, stream>>>(pv, out, 0);
    } else if (ws_size >= need2) {
        uint2* pv = (uint2*)d_ws;
        for (int p = 0; p < 2; p++) {
            pad_kernel<<<dim3(2 * PV_ROWS), dim3(256), 0, stream>>>(vol, pv, 4 * p);
            proj_kernel<2><<<dim3((N_VIEW / NV) * (N_DET / DG)), dim3(256), 0, stream>>>(pv, out, 4 * p);
        }
    } else {
        proj_fallback<<<dim3(N_VIEW * 8), dim3(256), 0, stream>>>(vol, out);
    }
}

// Round 10
// 337.575 us; speedup vs baseline: 8.6008x; 1.1593x over previous
//
#include <hip/hip_runtime.h>
#include <hip/hip_fp16.h>
#include <math.h>

#define N_IMG  512
#define N_Z    8
#define N_VIEW 360
#define N_DET  512
#define N_S    512
#define SLICE  (N_IMG * N_IMG)

// Padded fp16 vertical-pair volume in ws (R8 layout, measured-good banks):
//   PV[z][r][c] = half2( P(r-2, c-2), P(r-1, c-2) ),  P = vol zero-padded.
// r in [0,514] covers pair-row civ in [-2,512]; c in [0,515] covers ciu in [-2,513].
#define PV_ROWS    515
#define PV_PITCH   516
#define PV_ZSTRIDE (PV_ROWS * PV_PITCH)   // u32 cells
#define NV 4          // views per block (one per wave)
#define DG 32         // detectors per block
#define SC 32         // s samples per chunk
#define NCHUNK (N_S / SC)
#define ST 68         // cells/LDS row: 272B = 17 x 16B (DMA-tileable), banks (4*civ+ciu)%32
#define CELLS 4096    // per buffer; 16 dma16-instrs x 64 lanes x 16B = 16KB exactly

typedef _Float16 half2v __attribute__((ext_vector_type(2)));

__device__ __forceinline__ void dma16(const unsigned* g, unsigned* l) {
    // async global->LDS, 16B/lane; LDS dest = wave-uniform base + lane*16
    __builtin_amdgcn_global_load_lds((const __attribute__((address_space(1))) unsigned*)g,
                                     (__attribute__((address_space(3))) unsigned*)l,
                                     16, 0, 0);
}

__global__ __launch_bounds__(256) void pad_kernel(const float* __restrict__ vol,
                                                  unsigned* __restrict__ pv) {
    const int zr = blockIdx.x;                  // 0 .. 8*PV_ROWS-1
    const int z  = zr / PV_ROWS;
    const int r  = zr - z * PV_ROWS;
    const float* __restrict__ img = vol + (size_t)z * SLICE;
    unsigned* __restrict__ dst = pv + (size_t)z * PV_ZSTRIDE + (size_t)r * PV_PITCH;
    const int y0 = r - 2, y1 = r - 1;
    const bool y0ok = (unsigned)y0 < (unsigned)N_IMG;
    const bool y1ok = (unsigned)y1 < (unsigned)N_IMG;
    for (int c = threadIdx.x; c < PV_PITCH; c += 256) {
        const int x = c - 2;
        const bool xok = (unsigned)x < (unsigned)N_IMG;
        const float v0 = (y0ok && xok) ? img[y0 * N_IMG + x] : 0.0f;
        const float v1 = (y1ok && xok) ? img[y1 * N_IMG + x] : 0.0f;
        __half2 h;
        h.x = __float2half(v0);
        h.y = __float2half(v1);
        dst[c] = *reinterpret_cast<unsigned*>(&h);
    }
}

// Stage one z window (rows 0..59 full, 68 cells/row) with 16 dma16 (4/wave),
// all 64 lanes active; per-thread (row,k) geometry precomputed in dmarow/dmak.
#define DMA_WINDOW(Z, B)                                                      \
    {                                                                         \
        const unsigned* __restrict__ pvz = pv + (size_t)(Z) * PV_ZSTRIDE;     \
        _Pragma("unroll")                                                     \
        for (int i = 0; i < 4; i++) {                                         \
            const int rowg = min(v0p2 + dmarow[i], PV_ROWS - 1);              \
            dma16(pvz + (size_t)rowg * PV_PITCH + (u0p2 + dmak[i]),           \
                  &sm[B][(wvid * 4 + i) * 256]);                              \
        }                                                                     \
    }

// One sample: 2x ds_read_b32 (vertical-pair cells ciu, ciu+1), pk lerp, fdot2.
#define GATHER(Z, B)                                                          \
    {                                                                         \
        _Pragma("unroll")                                                     \
        for (int dd = 0; dd < 4; dd++) if (act[dd]) {                         \
            _Pragma("unroll")                                                 \
            for (int ks = 0; ks < 4; ks++) {                                  \
                const int o = offs[dd][ks];                                   \
                const unsigned p0 = sm[B][o], p1 = sm[B][o + 1];              \
                const half2v h0 = __builtin_bit_cast(half2v, p0);             \
                const half2v h1 = __builtin_bit_cast(half2v, p1);             \
                const half2v rr = h0 + wu2a[dd][ks] * (h1 - h0);              \
                acc[dd][Z] = __builtin_amdgcn_fdot2(rr, wv2a[dd][ks],         \
                                                    acc[dd][Z], false);       \
            }                                                                 \
        }                                                                     \
    }

// Block: 4 views (one per wave) x 32 dets x full s. Lane = 8 dets x 8 s-phases.
// All 8 z per dispatch (sample setup computed once, reused 8x).
// Double-buffered windows + counted vmcnt(4) + RAW barriers: __syncthreads would
// drain vmcnt(0) and serialize staging (R9 lesson); raw s_barrier keeps the
// z+1 prefetch in flight under gather(z)  [T3/T4, m201 precedent].
__global__ __launch_bounds__(256, 2) void proj_kernel(const unsigned* __restrict__ pv,
                                                      float* __restrict__ out) {
    __shared__ unsigned sm[2][CELLS];

    const int g    = blockIdx.x >> 4;          // view group 0..89
    const int dg   = blockIdx.x & 15;          // det group 0..15
    const int tid  = threadIdx.x;
    const int wvid = tid >> 6;                 // wave -> view
    const int lane = tid & 63;
    const int kp   = lane & 7;                 // s-phase (also the output z)
    const int tl   = lane >> 3;                // det-lane 0..7
    const int view = g * NV + wvid;

    // Per-thread DMA geometry: seg -> (row, cell) inside the 60x68 window.
    int dmarow[4], dmak[4];
    #pragma unroll
    for (int i = 0; i < 4; i++) {
        const int seg = (wvid * 4 + i) * 64 + lane;   // 16B segments, 17/row
        dmarow[i] = seg / 17;
        dmak[i]   = (seg - dmarow[i] * 17) * 4;       // cell offset in row
    }

    const float KTH = (float)(M_PI / 360.0);
    float c0, s0, c1, s1, c2, s2, c3, s3;
    sincosf((float)(g * 4 + 0) * KTH, &s0, &c0);
    sincosf((float)(g * 4 + 1) * KTH, &s1, &c1);
    sincosf((float)(g * 4 + 2) * KTH, &s2, &c2);
    sincosf((float)(g * 4 + 3) * KTH, &s3, &c3);
    const float c_my = (wvid == 0) ? c0 : (wvid == 1) ? c1 : (wvid == 2) ? c2 : c3;
    const float s_my = (wvid == 0) ? s0 : (wvid == 1) ? s1 : (wvid == 2) ? s2 : s3;

    const float t_base = (float)(dg * DG) - 255.5f;
    float buv[4], bvv[4];
    #pragma unroll
    for (int dd = 0; dd < 4; dd++) {
        const float tt = t_base + (float)(dd * 8 + tl);
        buv[dd] = fmaf(-s_my, tt, 255.5f);     // u = c*s + buv
        bvv[dd] = fmaf( c_my, tt, 255.5f);     // v = si*s + bvv
    }

    float acc[4][N_Z];
    #pragma unroll
    for (int dd = 0; dd < 4; dd++)
        #pragma unroll
        for (int zz = 0; zz < N_Z; zz++) acc[dd][zz] = 0.0f;

    for (int ck = 0; ck < NCHUNK; ++ck) {
        const float sA = (float)(ck * SC) - 255.5f;
        const float sB = sA + (float)(SC - 1);
        const float tA = t_base, tB = t_base + (float)(DG - 1);

        // Union bbox over the 4 views (block-uniform).
        float umin = 1e30f, umax = -1e30f, vmin = 1e30f, vmax = -1e30f;
        #pragma unroll
        for (int i = 0; i < 4; i++) {
            const float ci = (i == 0) ? c0 : (i == 1) ? c1 : (i == 2) ? c2 : c3;
            const float si = (i == 0) ? s0 : (i == 1) ? s1 : (i == 2) ? s2 : s3;
            const float ua = ci * sA, ub = ci * sB;
            const float uc = -si * tA, ud = -si * tB;
            umin = fminf(umin, fminf(ua, ub) + fminf(uc, ud));
            umax = fmaxf(umax, fmaxf(ua, ub) + fmaxf(uc, ud));
            const float va = si * sA, vb = si * sB;
            const float vc = ci * tA, vd = ci * tB;
            vmin = fminf(vmin, fminf(va, vb) + fminf(vc, vd));
            vmax = fmaxf(vmax, fmaxf(va, vb) + fmaxf(vc, vd));
        }
        umin += 255.5f; umax += 255.5f; vmin += 255.5f; vmax += 255.5f;

        int u0 = max((int)floorf(umin) - 1, -2);
        u0 = ((u0 + 2) & ~3) - 2;                      // 16B-align DMA columns
        const int uend = min((int)floorf(umax) + 2, 513);
        const int v0   = max((int)floorf(vmin) - 1, -2);
        const int vend = min((int)floorf(vmax) + 1, 512);
        if (uend < u0 || vend < v0) continue;          // block-uniform

        // Per-thread sample offsets + packed fp16 weights (shared across 8 z).
        int    offs[4][4];
        half2v wu2a[4][4], wv2a[4][4];
        bool   act[4];
        #pragma unroll
        for (int dd = 0; dd < 4; dd++) {
            const float uA = fmaf(c_my, sA, buv[dd]), uB = fmaf(c_my, sB, buv[dd]);
            const float vA = fmaf(s_my, sA, bvv[dd]), vB = fmaf(s_my, sB, bvv[dd]);
            const float ulo = fminf(uA, uB), uhi = fmaxf(uA, uB);
            const float vlo = fminf(vA, vB), vhi = fmaxf(vA, vB);
            act[dd] = (uhi > -1.0f) && (ulo < 512.0f) && (vhi > -1.0f) && (vlo < 512.0f);
            if (act[dd]) {
                #pragma unroll
                for (int ks = 0; ks < 4; ks++) {
                    const float s = sA + (float)(ks * 8 + kp);
                    const float u = fmaf(c_my, s, buv[dd]);
                    const float v = fmaf(s_my, s, bvv[dd]);
                    const float fu = floorf(u), fv = floorf(v);
                    const _Float16 wuh = (_Float16)(u - fu);
                    const _Float16 wvh = (_Float16)(v - fv);
                    wu2a[dd][ks] = (half2v){wuh, wuh};
                    wv2a[dd][ks] = (half2v){(_Float16)((_Float16)1.0f - wvh), wvh};
                    const int ciu = min(max((int)fu, -2), 512);  // clamped cells are zeros
                    const int civ = min(max((int)fv, -2), 512);
                    offs[dd][ks] = (civ - v0) * ST + (ciu - u0);
                }
            }
        }

        const int u0p2 = u0 + 2;   // multiple of 4 -> 16B-aligned global segs
        const int v0p2 = v0 + 2;

        DMA_WINDOW(0, 0);
        #pragma unroll
        for (int z = 0; z < N_Z; z++) {
            if (z < 7) { DMA_WINDOW(z + 1, (z + 1) & 1); }   // prefetch next z
            if (z < 7) asm volatile("s_waitcnt vmcnt(4)" ::: "memory");
            else       asm volatile("s_waitcnt vmcnt(0)" ::: "memory");
            __builtin_amdgcn_s_barrier();                    // window z visible
            GATHER(z, z & 1);
            __builtin_amdgcn_s_barrier();                    // reads done before overwrite
        }
    }

    // Reduce the 8 s-phases; lane kp writes z = kp (all lanes write one output).
    #pragma unroll
    for (int dd = 0; dd < 4; dd++) {
        #pragma unroll
        for (int zz = 0; zz < N_Z; zz++) {
            float a = acc[dd][zz];
            a += __shfl_xor(a, 1);
            a += __shfl_xor(a, 2);
            a += __shfl_xor(a, 4);
            acc[dd][zz] = a;
        }
        float val = acc[dd][0];
        #pragma unroll
        for (int zz = 1; zz < N_Z; zz++)
            if (kp == zz) val = acc[dd][zz];
        const int det = dg * DG + dd * 8 + tl;
        out[((size_t)(kp * N_VIEW + view)) * N_DET + det] = val;
    }
}

// ---------------- fallback (Round-5 kernel, no ws needed) ----------------
#define FDG 64
#define FSC 32
#define FNC (N_S / FSC)
#define FROWS 76
#define FSTR  81

__global__ __launch_bounds__(256) void proj_fallback(const float* __restrict__ vol,
                                                     float* __restrict__ out) {
    __shared__ float sm[FROWS * FSTR];
    const int bid  = blockIdx.x;
    const int view = bid >> 3;
    const int dg   = bid & 7;
    const int tid  = threadIdx.x;
    const int lane = tid & 63;
    const int wvid = tid >> 6;
    const int kp   = lane & 3;
    const int tl   = lane >> 2;
    const int det  = dg * FDG + wvid * 16 + tl;

    const float theta = (float)view * (float)(M_PI / 360.0);
    float si, c;
    sincosf(theta, &si, &c);
    const float t  = (float)det - 255.5f;
    const float bu = fmaf(-si, t, 255.5f);
    const float bv = fmaf( c,  t, 255.5f);

    float lo = -1e30f, hi = 1e30f;
    if (fabsf(c) > 1e-7f) {
        float a = (-1.0f - bu) / c, b = (512.0f - bu) / c;
        lo = fmaxf(lo, fminf(a, b)); hi = fminf(hi, fmaxf(a, b));
    } else if (bu <= -1.0f || bu >= 512.0f) { lo = 1e30f; hi = -1e30f; }
    if (fabsf(si) > 1e-7f) {
        float a = (-1.0f - bv) / si, b = (512.0f - bv) / si;
        lo = fmaxf(lo, fminf(a, b)); hi = fminf(hi, fmaxf(a, b));
    } else if (bv <= -1.0f || bv >= 512.0f) { lo = 1e30f; hi = -1e30f; }
    int klo = 0, khi = -1;
    if (hi >= lo) {
        klo = max(0, (int)floorf(lo + 255.5f) - 1);
        khi = min(N_S - 1, (int)ceilf(hi + 255.5f) + 1);
    }
    const float tA = (float)(dg * FDG) - 255.5f;
    const float tB = tA + (float)(FDG - 1);

    float acc[N_Z];
    #pragma unroll
    for (int z = 0; z < N_Z; z++) acc[z] = 0.0f;

    for (int ck = 0; ck < FNC; ++ck) {
        const int kbase = ck * FSC;
        const float sA = -255.5f + (float)kbase;
        const float sB = sA + (float)(FSC - 1);
        const float buA = fmaf(-si, tA, 255.5f), buB = fmaf(-si, tB, 255.5f);
        const float bvA = fmaf( c,  tA, 255.5f), bvB = fmaf( c,  tB, 255.5f);
        const float u00 = fmaf(c, sA, buA), u01 = fmaf(c, sB, buA);
        const float u10 = fmaf(c, sA, buB), u11 = fmaf(c, sB, buB);
        const float v00 = fmaf(si, sA, bvA), v01 = fmaf(si, sB, bvA);
        const float v10 = fmaf(si, sA, bvB), v11 = fmaf(si, sB, bvB);
        const float umin = fminf(fminf(u00, u01), fminf(u10, u11));
        const float umax = fmaxf(fmaxf(u00, u01), fmaxf(u10, u11));
        const float vmin = fminf(fminf(v00, v01), fminf(v10, v11));
        const float vmax = fmaxf(fmaxf(v00, v01), fmaxf(v10, v11));
        const int u0c = (int)floorf(umin) - 1;
        const int v0c = (int)floorf(vmin) - 1;
        int WU = (int)floorf(umax) - u0c + 2;
        int WV = (int)floorf(vmax) - v0c + 2;
        WU = min(WU, FSTR - 1); WV = min(WV, FROWS);
        if (u0c >= N_IMG || v0c >= N_IMG || u0c + WU <= 0 || v0c + WV <= 0) continue;
        const bool active = (klo <= kbase + FSC - 1) && (khi >= kbase);
        int offs[8]; float wus[8], wvs[8];
        if (active) {
            #pragma unroll
            for (int j = 0; j < 8; j++) {
                const int k = kbase + j * 4 + kp;
                const float s = -255.5f + (float)k;
                const float u = fmaf(c, s, bu), v = fmaf(si, s, bv);
                const float fu = floorf(u), fv = floorf(v);
                wus[j] = u - fu; wvs[j] = v - fv;
                offs[j] = ((int)fv - v0c) * FSTR + ((int)fu - u0c);
            }
        }
        const int cnt = __syncthreads_count(active ? 1 : 0);
        if (cnt == 0) continue;
        #pragma unroll
        for (int z = 0; z < N_Z; ++z) {
            const float* __restrict__ img = vol + (size_t)z * SLICE;
            for (int j = wvid; j < WV; j += 4) {
                const int r = v0c + j;
                const bool rok = (unsigned)r < (unsigned)N_IMG;
                float* dstrow = &sm[j * FSTR];
                if (lane < WU) {
                    const int cc = u0c + lane;
                    float vl = 0.0f;
                    if (rok && (unsigned)cc < (unsigned)N_IMG) vl = img[r * N_IMG + cc];
                    dstrow[lane] = vl;
                }
                if (lane < WU - 64) {
                    const int cc = u0c + 64 + lane;
                    float vl = 0.0f;
                    if (rok && (unsigned)cc < (unsigned)N_IMG) vl = img[r * N_IMG + cc];
                    dstrow[64 + lane] = vl;
                }
            }
            __syncthreads();
            if (active) {
                #pragma unroll
                for (int j = 0; j < 8; j++) {
                    const int o = offs[j];
                    const float a00 = sm[o], a01 = sm[o + 1];
                    const float a10 = sm[o + FSTR], a11 = sm[o + FSTR + 1];
                    const float wu = wus[j], wv2 = wvs[j];
                    const float top = fmaf(wu, a01 - a00, a00);
                    const float bot = fmaf(wu, a11 - a10, a10);
                    acc[z] = fmaf(wv2, bot - top, acc[z] + top);
                }
            }
            __syncthreads();
        }
    }
    #pragma unroll
    for (int z = 0; z < N_Z; z++) {
        acc[z] += __shfl_xor(acc[z], 1);
        acc[z] += __shfl_xor(acc[z], 2);
    }
    #pragma unroll
    for (int j = 0; j < 2; j++) {
        const int zt = kp * 2 + j;
        float val = 0.0f;
        #pragma unroll
        for (int zz = 0; zz < N_Z; zz++)
            if (zz == zt) val = acc[zz];
        out[((size_t)(zt * N_VIEW + view)) * N_DET + det] = val;
    }
}

extern "C" void kernel_launch(void* const* d_in, const int* in_sizes, int n_in,
                              void* d_out, int out_size, void* d_ws, size_t ws_size,
                              hipStream_t stream) {
    const float* vol = (const float*)d_in[0];
    float* out = (float*)d_out;
    (void)in_sizes; (void)n_in; (void)out_size;

    // +4KB slack: row-clamped DMA tails can overrun the last slice by < 1KB.
    const size_t need = (size_t)N_Z * PV_ZSTRIDE * sizeof(unsigned) + 4096;  // ~8.5 MB
    if (ws_size >= need) {
        unsigned* pv = (unsigned*)d_ws;
        pad_kernel<<<dim3(N_Z * PV_ROWS), dim3(256), 0, stream>>>(vol, pv);
        proj_kernel<<<dim3((N_VIEW / NV) * (N_DET / DG)), dim3(256), 0, stream>>>(pv, out);
    } else {
        proj_fallback<<<dim3(N_VIEW * 8), dim3(256), 0, stream>>>(vol, out);
    }
}